// Round 1
// baseline (4980.728 us; speedup 1.0000x reference)
//
#include <hip/hip_runtime.h>

typedef __bf16 bf16x8 __attribute__((ext_vector_type(8)));
typedef float  f32x4  __attribute__((ext_vector_type(4)));

__device__ __forceinline__ float sigm(float x) { return 1.0f / (1.0f + __expf(-x)); }
__device__ __forceinline__ float tanh_(float x) {
  x = fminf(fmaxf(x, -15.0f), 15.0f);
  float e = __expf(-2.0f * x);
  return (1.0f - e) / (1.0f + e);
}

// ---------------------------------------------------------------------------
// Weight prep: reorder gate rows g = gate*256+d  ->  g' = (d/16)*48 + gate*16 + (d%16)
// so each 16-wide MFMA N-tile holds one gate for 16 consecutive hidden units.
// Also converts Wih/Whh to bf16 and splits biases.
// ---------------------------------------------------------------------------
__global__ __launch_bounds__(256) void prep_layer(
    const float* __restrict__ Wih, const float* __restrict__ Whh,
    const float* __restrict__ bsrc, int Kin,
    __bf16* __restrict__ wih_o, __bf16* __restrict__ whh_o,
    float* __restrict__ bih_o, float* __restrict__ bhh_o)
{
  int r = blockIdx.x;                 // 0..1535 (dir-major, g'-order)
  int dir = (r >= 768) ? 1 : 0;
  int gp = r - dir * 768;
  int rem = gp % 48;
  int gate = rem >> 4;
  int d = (gp / 48) * 16 + (rem & 15);
  int g = gate * 256 + d;
  const float* src = Wih + ((size_t)dir * 768 + g) * Kin;
  __bf16* dst = wih_o + (size_t)r * Kin;
  for (int k = threadIdx.x; k < Kin; k += 256) dst[k] = (__bf16)src[k];
  const float* hs = Whh + ((size_t)dir * 768 + g) * 256;
  __bf16* hd = whh_o + (size_t)r * 256;
  hd[threadIdx.x] = (__bf16)hs[threadIdx.x];
  if (threadIdx.x == 0) {
    bih_o[r] = bsrc[(dir * 2 + 0) * 768 + g];
    bhh_o[r] = bsrc[(dir * 2 + 1) * 768 + g];
  }
}

// ---------------------------------------------------------------------------
// a[b,t] = c[b,t,:]·wc   and   e[b,j] = q[b,j,:]·wq    (one wave per dot)
// ---------------------------------------------------------------------------
__global__ __launch_bounds__(256) void k_dots(
    const float* __restrict__ c, const float* __restrict__ q,
    const float* __restrict__ Ws, float* __restrict__ a_g, float* __restrict__ e_g)
{
  const int wid = blockIdx.x * 4 + (threadIdx.x >> 6);
  const int lane = threadIdx.x & 63;
  const float* x; const float* wv; float* o;
  if (wid < 4096) { x = q + (size_t)wid * 512; wv = Ws + 512; o = e_g + wid; }
  else { int id = wid - 4096; x = c + (size_t)id * 512; wv = Ws; o = a_g + id; }
  float s = 0.f;
  #pragma unroll
  for (int i = 0; i < 8; ++i) s = fmaf(x[lane * 8 + i], wv[lane * 8 + i], s);
  #pragma unroll
  for (int off = 32; off; off >>= 1) s += __shfl_xor(s, off);
  if (lane == 0) *o = s;
}

// ---------------------------------------------------------------------------
// Fused attention main: per (b, t-half). Stages q[b] (f32, 513-padded rows) in
// LDS; per t computes the S row, softmax over j, c2q, and writes G[:,0:1536].
// Row-max of S goes to smax_g for the q2c softmax-over-t.
// ---------------------------------------------------------------------------
__global__ __launch_bounds__(512) void k_att_main(
    const float* __restrict__ c, const float* __restrict__ q,
    const float* __restrict__ Ws, const float* __restrict__ a_g,
    const float* __restrict__ e_g, float* __restrict__ smax_g,
    __bf16* __restrict__ G)
{
  constexpr int QSTR = 513;          // odd stride -> conflict-free column walks
  __shared__ float q_s[64 * QSTR];
  __shared__ float c_s[512], cw_s[512], sP[64], e_s[64], sred[512];
  const int b = blockIdx.y, th = blockIdx.x;
  const int tid = threadIdx.x;
  const float* qb = q + (size_t)b * 64 * 512;
  for (int i = tid; i < 64 * 512; i += 512) q_s[(i >> 9) * QSTR + (i & 511)] = qb[i];
  if (tid < 64) e_s[tid] = e_g[b * 64 + tid];
  __syncthreads();
  const int p = tid >> 6;            // wave id = d-block
  const int j = tid & 63;
  for (int tt = 0; tt < 128; ++tt) {
    const int t = th * 128 + tt;
    float cv = c[((size_t)b * 256 + t) * 512 + tid];
    c_s[tid] = cv;
    cw_s[tid] = cv * Ws[1024 + tid]; // * wm
    __syncthreads();
    { // S partials: wave p covers d in [p*64, p*64+64) for all 64 j
      const float* qrow = &q_s[j * QSTR + p * 64];
      const float* cw = &cw_s[p * 64];
      float s = 0.f;
      #pragma unroll
      for (int i = 0; i < 64; ++i) s = fmaf(cw[i], qrow[i], s);
      sred[p * 64 + j] = s;
    }
    __syncthreads();
    if (tid < 64) {
      float s = sred[tid] + sred[64 + tid] + sred[128 + tid] + sred[192 + tid]
              + sred[256 + tid] + sred[320 + tid] + sred[384 + tid] + sred[448 + tid];
      s += a_g[b * 256 + t] + e_s[tid];
      float m = s;
      #pragma unroll
      for (int off = 32; off; off >>= 1) m = fmaxf(m, __shfl_xor(m, off));
      float e = __expf(s - m);
      float sum = e;
      #pragma unroll
      for (int off = 32; off; off >>= 1) sum += __shfl_xor(sum, off);
      sP[tid] = e / sum;
      if (tid == 0) smax_g[b * 256 + t] = m;
    }
    __syncthreads();
    { // c2q + G blocks 0..2
      float acc = 0.f;
      #pragma unroll 8
      for (int jj = 0; jj < 64; ++jj) acc = fmaf(sP[jj], q_s[jj * QSTR + tid], acc);
      float cval = c_s[tid];
      __bf16* Gr = G + ((size_t)b * 256 + t) * 2560;
      Gr[tid]        = (__bf16)cval;
      Gr[512 + tid]  = (__bf16)acc;
      Gr[1024 + tid] = (__bf16)(cval * acc);
    }
    __syncthreads();
  }
}

// ---------------------------------------------------------------------------
// q2c: softmax over t of smax, q2c = sum_t w[t]*c[b,t,:]; writes G[:,1536:2048]
// ---------------------------------------------------------------------------
__global__ __launch_bounds__(256) void k_att_tail(
    const float* __restrict__ c, const float* __restrict__ smax_g,
    __bf16* __restrict__ G)
{
  __shared__ float w_s[256];
  __shared__ float red[8];
  const int b = blockIdx.x, tid = threadIdx.x;
  const int lane = tid & 63, wv = tid >> 6;
  float v = smax_g[b * 256 + tid];
  float m = v;
  #pragma unroll
  for (int off = 32; off; off >>= 1) m = fmaxf(m, __shfl_xor(m, off));
  if (lane == 0) red[wv] = m;
  __syncthreads();
  m = fmaxf(fmaxf(red[0], red[1]), fmaxf(red[2], red[3]));
  float e = __expf(v - m);
  float s = e;
  #pragma unroll
  for (int off = 32; off; off >>= 1) s += __shfl_xor(s, off);
  if (lane == 0) red[4 + wv] = s;
  __syncthreads();
  s = red[4] + red[5] + red[6] + red[7];
  w_s[tid] = e / s;
  __syncthreads();
  float q0 = 0.f, q1 = 0.f;
  for (int t = 0; t < 256; ++t) {
    const float* cr = c + ((size_t)b * 256 + t) * 512;
    q0 = fmaf(w_s[t], cr[tid], q0);
    q1 = fmaf(w_s[t], cr[tid + 256], q1);
  }
  for (int t = 0; t < 256; ++t) {
    const float* cr = c + ((size_t)b * 256 + t) * 512;
    __bf16* Gr = G + ((size_t)b * 256 + t) * 2560 + 1536;
    Gr[tid]       = (__bf16)(cr[tid] * q0);
    Gr[tid + 256] = (__bf16)(cr[tid + 256] * q1);
  }
}

// ---------------------------------------------------------------------------
// GEMM: C[M,1536] = A[M,K] @ Bw[1536,K]^T + bias.  128x128 tile, BK=32,
// 4 waves, 16x16x32 bf16 MFMA. LDS in k-group-major [kg][row][8] layout
// (2-way read conflicts only). A is bf16 row-major with stride lda.
// ---------------------------------------------------------------------------
__global__ __launch_bounds__(256) void gemm_bt(
    const __bf16* __restrict__ A, int lda,
    const __bf16* __restrict__ Bw, const float* __restrict__ bias,
    float* __restrict__ C, int K)
{
  __shared__ __align__(16) __bf16 As[4096], Bs[4096];
  const int tid = threadIdx.x;
  const int lane = tid & 63, w = tid >> 6;
  const int l15 = lane & 15, lq = lane >> 4;
  const int wm = w >> 1, wn = w & 1;
  const size_t bm = (size_t)blockIdx.x * 128;
  const size_t bn = (size_t)blockIdx.y * 128;
  const int srow = tid >> 2, skg = tid & 3;
  const __bf16* Ag0 = A + (bm + srow) * lda + skg * 8;
  const __bf16* Ag1 = Ag0 + (size_t)64 * lda;
  const __bf16* Bg0 = Bw + (bn + srow) * (size_t)K + skg * 8;
  const __bf16* Bg1 = Bg0 + (size_t)64 * K;
  f32x4 acc[4][4] = {};
  const int nkt = K >> 5;
  for (int kt = 0; kt < nkt; ++kt) {
    const int ko = kt * 32;
    bf16x8 av0 = *(const bf16x8*)(Ag0 + ko);
    bf16x8 av1 = *(const bf16x8*)(Ag1 + ko);
    bf16x8 bv0 = *(const bf16x8*)(Bg0 + ko);
    bf16x8 bv1 = *(const bf16x8*)(Bg1 + ko);
    __syncthreads();
    *(bf16x8*)&As[(skg * 128 + srow) * 8] = av0;
    *(bf16x8*)&As[(skg * 128 + srow + 64) * 8] = av1;
    *(bf16x8*)&Bs[(skg * 128 + srow) * 8] = bv0;
    *(bf16x8*)&Bs[(skg * 128 + srow + 64) * 8] = bv1;
    __syncthreads();
    bf16x8 af[4], bfv[4];
    #pragma unroll
    for (int f = 0; f < 4; ++f) {
      af[f]  = *(const bf16x8*)&As[(lq * 128 + wm * 64 + f * 16 + l15) * 8];
      bfv[f] = *(const bf16x8*)&Bs[(lq * 128 + wn * 64 + f * 16 + l15) * 8];
    }
    #pragma unroll
    for (int fm = 0; fm < 4; ++fm)
      #pragma unroll
      for (int fn = 0; fn < 4; ++fn)
        acc[fm][fn] = __builtin_amdgcn_mfma_f32_16x16x32_bf16(af[fm], bfv[fn], acc[fm][fn], 0, 0, 0);
  }
  float bv[4];
  #pragma unroll
  for (int fn = 0; fn < 4; ++fn) bv[fn] = bias[bn + wn * 64 + fn * 16 + l15];
  #pragma unroll
  for (int fm = 0; fm < 4; ++fm)
    #pragma unroll
    for (int fn = 0; fn < 4; ++fn)
      #pragma unroll
      for (int r = 0; r < 4; ++r) {
        size_t row = bm + wm * 64 + fm * 16 + lq * 4 + r;
        size_t col = bn + wn * 64 + fn * 16 + l15;
        C[row * 1536 + col] = acc[fm][fn][r] + bv[fn];
      }
}

// ---------------------------------------------------------------------------
// GRU recurrence: one WG of 512 threads per (dir, 16-batch group). 8 waves,
// wave w owns hidden units d in [w*32, w*32+32) = 6 MFMA tiles (2 d-groups x
// {r,z,n}). Whh' (g'-reordered bf16) streamed from L2 each step. h double-
// buffered in LDS (bf16, 528B row stride -> 2-way conflicts only).
// One barrier per step.
// ---------------------------------------------------------------------------
__global__ __launch_bounds__(512) void gru_rec(
    const float* __restrict__ gi, const __bf16* __restrict__ whh,
    const float* __restrict__ bhh, __bf16* __restrict__ ys, int ys_stride,
    float* __restrict__ out_final)
{
  constexpr int HSTR = 264;          // bf16 elems per h row (256 + 8 pad)
  __shared__ __align__(16) __bf16 h_lds[2][16 * HSTR];
  const int tid = threadIdx.x;
  const int w = tid >> 6, lane = tid & 63;
  const int l15 = lane & 15, lq = lane >> 4;
  const int dir = blockIdx.y;
  const int b0 = blockIdx.x * 16;

  for (int i = tid; i < 2 * 16 * HSTR; i += 512) (&h_lds[0][0])[i] = (__bf16)0.0f;

  const __bf16* wp[2][3];
  float bh[2][3];
  #pragma unroll
  for (int dg = 0; dg < 2; ++dg)
    #pragma unroll
    for (int gt = 0; gt < 3; ++gt) {
      int gp = (2 * w + dg) * 48 + gt * 16 + l15;
      wp[dg][gt] = whh + ((size_t)dir * 768 + gp) * 256;
      bh[dg][gt] = bhh[dir * 768 + gp];
    }
  const float* gp_[4];
  #pragma unroll
  for (int r = 0; r < 4; ++r) {
    int b = b0 + lq * 4 + r;
    gp_[r] = gi + (size_t)b * 256 * 1536 + dir * 768 + w * 96 + l15;
  }
  __bf16* yp[4];
  if (ys) {
    #pragma unroll
    for (int r = 0; r < 4; ++r) {
      int b = b0 + lq * 4 + r;
      yp[r] = ys + (size_t)b * 256 * ys_stride + dir * 256 + w * 32 + l15;
    }
  }
  float hprev[2][4] = {};
  int cur = 0;
  __syncthreads();

  for (int s = 0; s < 256; ++s) {
    const int t = dir ? (255 - s) : s;
    // gi loads (issued early; consumed ~2000 cycles later)
    float gv[2][3][4];
    #pragma unroll
    for (int r = 0; r < 4; ++r) {
      const float* gg = gp_[r] + (size_t)t * 1536;
      #pragma unroll
      for (int dg = 0; dg < 2; ++dg)
        #pragma unroll
        for (int gt = 0; gt < 3; ++gt)
          gv[dg][gt][r] = gg[dg * 48 + gt * 16];
    }
    // gh = h @ Whh'^T for this wave's 6 tiles
    f32x4 acc[2][3] = {};
    const __bf16* hb_ = &h_lds[cur][l15 * HSTR];
    #pragma unroll
    for (int ks = 0; ks < 8; ++ks) {
      bf16x8 af = *(const bf16x8*)(hb_ + ks * 32 + lq * 8);
      #pragma unroll
      for (int dg = 0; dg < 2; ++dg)
        #pragma unroll
        for (int gt = 0; gt < 3; ++gt) {
          bf16x8 wf = *(const bf16x8*)(wp[dg][gt] + ks * 32 + lq * 8);
          acc[dg][gt] = __builtin_amdgcn_mfma_f32_16x16x32_bf16(af, wf, acc[dg][gt], 0, 0, 0);
        }
    }
    // gates + h update (each lane owns 4 batches x 2 hidden units, full triplets)
    #pragma unroll
    for (int dg = 0; dg < 2; ++dg)
      #pragma unroll
      for (int r = 0; r < 4; ++r) {
        float rg = sigm(gv[dg][0][r] + acc[dg][0][r] + bh[dg][0]);
        float zg = sigm(gv[dg][1][r] + acc[dg][1][r] + bh[dg][1]);
        float ng = tanh_(gv[dg][2][r] + rg * (acc[dg][2][r] + bh[dg][2]));
        float h = (1.0f - zg) * ng + zg * hprev[dg][r];
        hprev[dg][r] = h;
        int bl = lq * 4 + r;
        int d = w * 32 + dg * 16 + l15;
        h_lds[cur ^ 1][bl * HSTR + d] = (__bf16)h;
        if (ys) yp[r][(size_t)t * ys_stride + dg * 16] = (__bf16)h;
      }
    __syncthreads();
    cur ^= 1;
  }
  if (!ys) {
    #pragma unroll
    for (int dg = 0; dg < 2; ++dg)
      #pragma unroll
      for (int r = 0; r < 4; ++r) {
        int b = b0 + lq * 4 + r;
        int d = w * 32 + dg * 16 + l15;
        out_final[(size_t)b * 512 + (dir ? 0 : 256) + d] = hprev[dg][r];
      }
  }
}

// ---------------------------------------------------------------------------
extern "C" void kernel_launch(void* const* d_in, const int* in_sizes, int n_in,
                              void* d_out, int out_size, void* d_ws, size_t ws_size,
                              hipStream_t stream) {
  (void)in_sizes; (void)n_in; (void)out_size; (void)ws_size;
  const float* c  = (const float*)d_in[0];
  const float* q  = (const float*)d_in[1];
  const float* Ws = (const float*)d_in[4];
  const float* w_ih[4] = { (const float*)d_in[5], (const float*)d_in[8],
                           (const float*)d_in[11], (const float*)d_in[14] };
  const float* w_hh[4] = { (const float*)d_in[6], (const float*)d_in[9],
                           (const float*)d_in[12], (const float*)d_in[15] };
  const float* b_l[4]  = { (const float*)d_in[7], (const float*)d_in[10],
                           (const float*)d_in[13], (const float*)d_in[16] };
  const int Kin[4] = {2048, 512, 2560, 512};

  char* ws = (char*)d_ws;
  size_t off = 0;
  auto alloc = [&](size_t bytes) -> void* {
    void* p = ws + off; off += (bytes + 255) & ~(size_t)255; return p;
  };
  __bf16* Gbuf = (__bf16*)alloc((size_t)16384 * 2560 * 2);  // [G | M] bf16
  float*  gi   = (float*) alloc((size_t)16384 * 1536 * 4);
  __bf16* m0   = (__bf16*)alloc((size_t)16384 * 512 * 2);
  __bf16* r0   = (__bf16*)alloc((size_t)16384 * 512 * 2);
  __bf16* wihp[4]; __bf16* whhp[4]; float* bihp[4]; float* bhhp[4];
  for (int l = 0; l < 4; ++l) {
    wihp[l] = (__bf16*)alloc((size_t)1536 * Kin[l] * 2);
    whhp[l] = (__bf16*)alloc((size_t)1536 * 256 * 2);
    bihp[l] = (float*)alloc(1536 * 4);
    bhhp[l] = (float*)alloc(1536 * 4);
  }
  float* e_g  = (float*)alloc(4096 * 4);
  float* a_g  = (float*)alloc(16384 * 4);
  float* smax = (float*)alloc(16384 * 4);

  for (int l = 0; l < 4; ++l)
    prep_layer<<<1536, 256, 0, stream>>>(w_ih[l], w_hh[l], b_l[l], Kin[l],
                                         wihp[l], whhp[l], bihp[l], bhhp[l]);
  k_dots<<<5120, 256, 0, stream>>>(c, q, Ws, a_g, e_g);
  k_att_main<<<dim3(2, 64), 512, 0, stream>>>(c, q, Ws, a_g, e_g, smax, Gbuf);
  k_att_tail<<<64, 256, 0, stream>>>(c, smax, Gbuf);

  // layer mod0: G(2048) -> m0
  gemm_bt<<<dim3(128, 12), 256, 0, stream>>>(Gbuf, 2560, wihp[0], bihp[0], gi, 2048);
  gru_rec<<<dim3(4, 2), 512, 0, stream>>>(gi, whhp[0], bhhp[0], m0, 512, nullptr);
  // layer mod1: m0(512) -> M (into Gbuf cols 2048:2560)
  gemm_bt<<<dim3(128, 12), 256, 0, stream>>>(m0, 512, wihp[1], bihp[1], gi, 512);
  gru_rec<<<dim3(4, 2), 512, 0, stream>>>(gi, whhp[1], bhhp[1], Gbuf + 2048, 2560, nullptr);
  // layer rep0: [G|M](2560) -> r0
  gemm_bt<<<dim3(128, 12), 256, 0, stream>>>(Gbuf, 2560, wihp[2], bihp[2], gi, 2560);
  gru_rec<<<dim3(4, 2), 512, 0, stream>>>(gi, whhp[2], bhhp[2], r0, 512, nullptr);
  // layer rep1: r0(512) -> final h only
  gemm_bt<<<dim3(128, 12), 256, 0, stream>>>(r0, 512, wihp[3], bihp[3], gi, 512);
  gru_rec<<<dim3(4, 2), 512, 0, stream>>>(gi, whhp[3], bhhp[3], nullptr, 0, (float*)d_out);
}

// Round 2
// 4176.027 us; speedup vs baseline: 1.1927x; 1.1927x over previous
//
#include <hip/hip_runtime.h>

typedef __bf16 bf16x8 __attribute__((ext_vector_type(8)));
typedef float  f32x4  __attribute__((ext_vector_type(4)));

__device__ __forceinline__ float sigm(float x) { return 1.0f / (1.0f + __expf(-x)); }
__device__ __forceinline__ float tanh_(float x) {
  x = fminf(fmaxf(x, -15.0f), 15.0f);
  float e = __expf(-2.0f * x);
  return (1.0f - e) / (1.0f + e);
}
__device__ __forceinline__ float bflo(unsigned u) { return __uint_as_float(u << 16); }
__device__ __forceinline__ float bfhi(unsigned u) { return __uint_as_float(u & 0xffff0000u); }

// ---------------------------------------------------------------------------
// Weight prep. Storage row order r'' (per dir): r'' = w*96 + l15*6 + (dg*3+gt)
// with hidden unit d = w*32 + dg*16 + l15 and source gate row g = gt*256 + d.
// This makes each lane's 6 gate pre-activations contiguous in gi.
// b_hh for r,z gates is folded into bih (GEMM bias); bhh_o keeps raw b_hh.
// ---------------------------------------------------------------------------
__global__ __launch_bounds__(256) void prep_layer(
    const float* __restrict__ Wih, const float* __restrict__ Whh,
    const float* __restrict__ bsrc, int Kin,
    __bf16* __restrict__ wih_o, __bf16* __restrict__ whh_o,
    float* __restrict__ bih_o, float* __restrict__ bhh_o)
{
  int R = blockIdx.x;                 // 0..1535 (dir-major, r''-order)
  int dir = (R >= 768) ? 1 : 0;
  int rp = R - dir * 768;
  int w = rp / 96, rem = rp % 96;
  int l15 = rem / 6, gx = rem % 6;
  int dg = gx / 3, gt = gx % 3;
  int d = w * 32 + dg * 16 + l15;
  int g = gt * 256 + d;
  const float* src = Wih + ((size_t)dir * 768 + g) * Kin;
  __bf16* dst = wih_o + (size_t)R * Kin;
  for (int k = threadIdx.x; k < Kin; k += 256) dst[k] = (__bf16)src[k];
  const float* hs = Whh + ((size_t)dir * 768 + g) * 256;
  __bf16* hd = whh_o + (size_t)R * 256;
  hd[threadIdx.x] = (__bf16)hs[threadIdx.x];
  if (threadIdx.x == 0) {
    float bih = bsrc[(dir * 2 + 0) * 768 + g];
    float bhh = bsrc[(dir * 2 + 1) * 768 + g];
    bih_o[R] = bih + (gt < 2 ? bhh : 0.0f);
    bhh_o[R] = bhh;
  }
}

// ---------------------------------------------------------------------------
// a[b,t] = c[b,t,:]·wc   and   e[b,j] = q[b,j,:]·wq    (one wave per dot)
// ---------------------------------------------------------------------------
__global__ __launch_bounds__(256) void k_dots(
    const float* __restrict__ c, const float* __restrict__ q,
    const float* __restrict__ Ws, float* __restrict__ a_g, float* __restrict__ e_g)
{
  const int wid = blockIdx.x * 4 + (threadIdx.x >> 6);
  const int lane = threadIdx.x & 63;
  const float* x; const float* wv; float* o;
  if (wid < 4096) { x = q + (size_t)wid * 512; wv = Ws + 512; o = e_g + wid; }
  else { int id = wid - 4096; x = c + (size_t)id * 512; wv = Ws; o = a_g + id; }
  float s = 0.f;
  #pragma unroll
  for (int i = 0; i < 8; ++i) s = fmaf(x[lane * 8 + i], wv[lane * 8 + i], s);
  #pragma unroll
  for (int off = 32; off; off >>= 1) s += __shfl_xor(s, off);
  if (lane == 0) *o = s;
}

// ---------------------------------------------------------------------------
// Fused attention main: per (b, t-half). Stages q[b] (f32, 513-padded rows) in
// LDS; per t computes the S row, softmax over j, c2q, and writes G[:,0:1536].
// ---------------------------------------------------------------------------
__global__ __launch_bounds__(512) void k_att_main(
    const float* __restrict__ c, const float* __restrict__ q,
    const float* __restrict__ Ws, const float* __restrict__ a_g,
    const float* __restrict__ e_g, float* __restrict__ smax_g,
    __bf16* __restrict__ G)
{
  constexpr int QSTR = 513;
  __shared__ float q_s[64 * QSTR];
  __shared__ float c_s[512], cw_s[512], sP[64], e_s[64], sred[512];
  const int b = blockIdx.y, th = blockIdx.x;
  const int tid = threadIdx.x;
  const float* qb = q + (size_t)b * 64 * 512;
  for (int i = tid; i < 64 * 512; i += 512) q_s[(i >> 9) * QSTR + (i & 511)] = qb[i];
  if (tid < 64) e_s[tid] = e_g[b * 64 + tid];
  __syncthreads();
  const int p = tid >> 6;
  const int j = tid & 63;
  for (int tt = 0; tt < 128; ++tt) {
    const int t = th * 128 + tt;
    float cv = c[((size_t)b * 256 + t) * 512 + tid];
    c_s[tid] = cv;
    cw_s[tid] = cv * Ws[1024 + tid];
    __syncthreads();
    {
      const float* qrow = &q_s[j * QSTR + p * 64];
      const float* cw = &cw_s[p * 64];
      float s = 0.f;
      #pragma unroll
      for (int i = 0; i < 64; ++i) s = fmaf(cw[i], qrow[i], s);
      sred[p * 64 + j] = s;
    }
    __syncthreads();
    if (tid < 64) {
      float s = sred[tid] + sred[64 + tid] + sred[128 + tid] + sred[192 + tid]
              + sred[256 + tid] + sred[320 + tid] + sred[384 + tid] + sred[448 + tid];
      s += a_g[b * 256 + t] + e_s[tid];
      float m = s;
      #pragma unroll
      for (int off = 32; off; off >>= 1) m = fmaxf(m, __shfl_xor(m, off));
      float e = __expf(s - m);
      float sum = e;
      #pragma unroll
      for (int off = 32; off; off >>= 1) sum += __shfl_xor(sum, off);
      sP[tid] = e / sum;
      if (tid == 0) smax_g[b * 256 + t] = m;
    }
    __syncthreads();
    {
      float acc = 0.f;
      #pragma unroll 8
      for (int jj = 0; jj < 64; ++jj) acc = fmaf(sP[jj], q_s[jj * QSTR + tid], acc);
      float cval = c_s[tid];
      __bf16* Gr = G + ((size_t)b * 256 + t) * 2560;
      Gr[tid]        = (__bf16)cval;
      Gr[512 + tid]  = (__bf16)acc;
      Gr[1024 + tid] = (__bf16)(cval * acc);
    }
    __syncthreads();
  }
}

// ---------------------------------------------------------------------------
// q2c tail: softmax over t of smax, q2c = sum_t w[t]*c[b,t,:]; G[:,1536:2048]
// ---------------------------------------------------------------------------
__global__ __launch_bounds__(256) void k_att_tail(
    const float* __restrict__ c, const float* __restrict__ smax_g,
    __bf16* __restrict__ G)
{
  __shared__ float w_s[256];
  __shared__ float red[8];
  const int b = blockIdx.x, tid = threadIdx.x;
  const int lane = tid & 63, wv = tid >> 6;
  float v = smax_g[b * 256 + tid];
  float m = v;
  #pragma unroll
  for (int off = 32; off; off >>= 1) m = fmaxf(m, __shfl_xor(m, off));
  if (lane == 0) red[wv] = m;
  __syncthreads();
  m = fmaxf(fmaxf(red[0], red[1]), fmaxf(red[2], red[3]));
  float e = __expf(v - m);
  float s = e;
  #pragma unroll
  for (int off = 32; off; off >>= 1) s += __shfl_xor(s, off);
  if (lane == 0) red[4 + wv] = s;
  __syncthreads();
  s = red[4] + red[5] + red[6] + red[7];
  w_s[tid] = e / s;
  __syncthreads();
  float q0 = 0.f, q1 = 0.f;
  for (int t = 0; t < 256; ++t) {
    const float* cr = c + ((size_t)b * 256 + t) * 512;
    q0 = fmaf(w_s[t], cr[tid], q0);
    q1 = fmaf(w_s[t], cr[tid + 256], q1);
  }
  for (int t = 0; t < 256; ++t) {
    const float* cr = c + ((size_t)b * 256 + t) * 512;
    __bf16* Gr = G + ((size_t)b * 256 + t) * 2560 + 1536;
    Gr[tid]       = (__bf16)(cr[tid] * q0);
    Gr[tid + 256] = (__bf16)(cr[tid + 256] * q1);
  }
}

// ---------------------------------------------------------------------------
// GEMM: C[M,1536] = A[M,K] @ Bw[1536,K]^T + bias, bf16 output.
// 128x128 tile, BK=32, 4 waves, 16x16x32 bf16 MFMA, k-group-major LDS.
// ---------------------------------------------------------------------------
__global__ __launch_bounds__(256) void gemm_bt(
    const __bf16* __restrict__ A, int lda,
    const __bf16* __restrict__ Bw, const float* __restrict__ bias,
    __bf16* __restrict__ C, int K)
{
  __shared__ __align__(16) __bf16 As[4096], Bs[4096];
  const int tid = threadIdx.x;
  const int lane = tid & 63, w = tid >> 6;
  const int l15 = lane & 15, lq = lane >> 4;
  const int wm = w >> 1, wn = w & 1;
  const size_t bm = (size_t)blockIdx.x * 128;
  const size_t bn = (size_t)blockIdx.y * 128;
  const int srow = tid >> 2, skg = tid & 3;
  const __bf16* Ag0 = A + (bm + srow) * lda + skg * 8;
  const __bf16* Ag1 = Ag0 + (size_t)64 * lda;
  const __bf16* Bg0 = Bw + (bn + srow) * (size_t)K + skg * 8;
  const __bf16* Bg1 = Bg0 + (size_t)64 * K;
  f32x4 acc[4][4] = {};
  const int nkt = K >> 5;
  for (int kt = 0; kt < nkt; ++kt) {
    const int ko = kt * 32;
    bf16x8 av0 = *(const bf16x8*)(Ag0 + ko);
    bf16x8 av1 = *(const bf16x8*)(Ag1 + ko);
    bf16x8 bv0 = *(const bf16x8*)(Bg0 + ko);
    bf16x8 bv1 = *(const bf16x8*)(Bg1 + ko);
    __syncthreads();
    *(bf16x8*)&As[(skg * 128 + srow) * 8] = av0;
    *(bf16x8*)&As[(skg * 128 + srow + 64) * 8] = av1;
    *(bf16x8*)&Bs[(skg * 128 + srow) * 8] = bv0;
    *(bf16x8*)&Bs[(skg * 128 + srow + 64) * 8] = bv1;
    __syncthreads();
    bf16x8 af[4], bfv[4];
    #pragma unroll
    for (int f = 0; f < 4; ++f) {
      af[f]  = *(const bf16x8*)&As[(lq * 128 + wm * 64 + f * 16 + l15) * 8];
      bfv[f] = *(const bf16x8*)&Bs[(lq * 128 + wn * 64 + f * 16 + l15) * 8];
    }
    #pragma unroll
    for (int fm = 0; fm < 4; ++fm)
      #pragma unroll
      for (int fn = 0; fn < 4; ++fn)
        acc[fm][fn] = __builtin_amdgcn_mfma_f32_16x16x32_bf16(af[fm], bfv[fn], acc[fm][fn], 0, 0, 0);
  }
  float bv[4];
  #pragma unroll
  for (int fn = 0; fn < 4; ++fn) bv[fn] = bias[bn + wn * 64 + fn * 16 + l15];
  #pragma unroll
  for (int fm = 0; fm < 4; ++fm)
    #pragma unroll
    for (int fn = 0; fn < 4; ++fn)
      #pragma unroll
      for (int r = 0; r < 4; ++r) {
        size_t row = bm + wm * 64 + fm * 16 + lq * 4 + r;
        size_t col = bn + wn * 64 + fn * 16 + l15;
        C[row * 1536 + col] = (__bf16)(acc[fm][fn][r] + bv[fn]);
      }
}

// ---------------------------------------------------------------------------
// GRU recurrence v2: all Whh' weights resident in VGPRs (192/lane); gi is
// bf16 gate-packed so each lane does 12 dword loads/step (in-step prefetch).
// One barrier per step; h double-buffered in LDS.
// ---------------------------------------------------------------------------
__global__ __launch_bounds__(512, 2) void gru_rec(
    const __bf16* __restrict__ gi, const __bf16* __restrict__ whh,
    const float* __restrict__ bhh, __bf16* __restrict__ ys, int ys_stride,
    float* __restrict__ out_final)
{
  constexpr int HSTR = 264;
  __shared__ __align__(16) __bf16 h_lds[2][16 * HSTR];
  const int tid = threadIdx.x;
  const int w = tid >> 6, lane = tid & 63;
  const int l15 = lane & 15, lq = lane >> 4;
  const int dir = blockIdx.y;
  const int b0 = blockIdx.x * 16;

  for (int i = tid; i < 2 * 16 * HSTR; i += 512) (&h_lds[0][0])[i] = (__bf16)0.0f;

  // all 6 weight tiles resident: wreg[dg][gt][ks]  (192 VGPRs)
  bf16x8 wreg[2][3][8];
  #pragma unroll
  for (int dg = 0; dg < 2; ++dg)
    #pragma unroll
    for (int gt = 0; gt < 3; ++gt) {
      const __bf16* wp = whh + ((size_t)dir * 768 + w * 96 + l15 * 6 + dg * 3 + gt) * 256 + lq * 8;
      #pragma unroll
      for (int ks = 0; ks < 8; ++ks)
        wreg[dg][gt][ks] = *(const bf16x8*)(wp + ks * 32);
    }
  float bhn0 = bhh[dir * 768 + w * 96 + l15 * 6 + 2];
  float bhn1 = bhh[dir * 768 + w * 96 + l15 * 6 + 5];

  const __bf16* gbase = gi + (size_t)(b0 + lq * 4) * 256 * 1536 + dir * 768 + w * 96 + l15 * 6;
  __bf16* ybase = ys ? (ys + (size_t)(b0 + lq * 4) * 256 * ys_stride + dir * 256 + w * 32 + l15)
                     : (__bf16*)0;

  float hprev[2][4] = {};
  int cur = 0;
  __syncthreads();

  for (int s = 0; s < 256; ++s) {
    const int t = dir ? (255 - s) : s;
    unsigned gw[4][3];
    #pragma unroll
    for (int r = 0; r < 4; ++r) {
      const unsigned* p = (const unsigned*)(gbase + (size_t)r * (256 * 1536) + (size_t)t * 1536);
      gw[r][0] = p[0]; gw[r][1] = p[1]; gw[r][2] = p[2];
    }
    f32x4 acc[2][3] = {};
    const __bf16* hb_ = &h_lds[cur][l15 * HSTR + lq * 8];
    #pragma unroll
    for (int ks = 0; ks < 8; ++ks) {
      bf16x8 af = *(const bf16x8*)(hb_ + ks * 32);
      #pragma unroll
      for (int dg = 0; dg < 2; ++dg)
        #pragma unroll
        for (int gt = 0; gt < 3; ++gt)
          acc[dg][gt] = __builtin_amdgcn_mfma_f32_16x16x32_bf16(af, wreg[dg][gt][ks], acc[dg][gt], 0, 0, 0);
    }
    #pragma unroll
    for (int dg = 0; dg < 2; ++dg)
      #pragma unroll
      for (int r = 0; r < 4; ++r) {
        float ir, iz, in_;
        if (dg == 0) { ir = bflo(gw[r][0]); iz = bfhi(gw[r][0]); in_ = bflo(gw[r][1]); }
        else         { ir = bfhi(gw[r][1]); iz = bflo(gw[r][2]); in_ = bfhi(gw[r][2]); }
        float bn_ = dg ? bhn1 : bhn0;
        float rg = sigm(ir + acc[dg][0][r]);
        float zg = sigm(iz + acc[dg][1][r]);
        float ng = tanh_(in_ + rg * (acc[dg][2][r] + bn_));
        float h = ng + zg * (hprev[dg][r] - ng);
        hprev[dg][r] = h;
        h_lds[cur ^ 1][(lq * 4 + r) * HSTR + w * 32 + dg * 16 + l15] = (__bf16)h;
        if (ys) ybase[(size_t)(r * 256 + t) * ys_stride + dg * 16] = (__bf16)h;
      }
    __syncthreads();
    cur ^= 1;
  }
  if (!ys) {
    #pragma unroll
    for (int dg = 0; dg < 2; ++dg)
      #pragma unroll
      for (int r = 0; r < 4; ++r)
        out_final[(size_t)(b0 + lq * 4 + r) * 512 + (dir ? 0 : 256) + w * 32 + dg * 16 + l15]
            = hprev[dg][r];
  }
}

// ---------------------------------------------------------------------------
extern "C" void kernel_launch(void* const* d_in, const int* in_sizes, int n_in,
                              void* d_out, int out_size, void* d_ws, size_t ws_size,
                              hipStream_t stream) {
  (void)in_sizes; (void)n_in; (void)out_size; (void)ws_size;
  const float* c  = (const float*)d_in[0];
  const float* q  = (const float*)d_in[1];
  const float* Ws = (const float*)d_in[4];
  const float* w_ih[4] = { (const float*)d_in[5], (const float*)d_in[8],
                           (const float*)d_in[11], (const float*)d_in[14] };
  const float* w_hh[4] = { (const float*)d_in[6], (const float*)d_in[9],
                           (const float*)d_in[12], (const float*)d_in[15] };
  const float* b_l[4]  = { (const float*)d_in[7], (const float*)d_in[10],
                           (const float*)d_in[13], (const float*)d_in[16] };
  const int Kin[4] = {2048, 512, 2560, 512};

  char* ws = (char*)d_ws;
  size_t off = 0;
  auto alloc = [&](size_t bytes) -> void* {
    void* p = ws + off; off += (bytes + 255) & ~(size_t)255; return p;
  };
  __bf16* Gbuf = (__bf16*)alloc((size_t)16384 * 2560 * 2);  // [G | M] bf16
  __bf16* gi   = (__bf16*)alloc((size_t)16384 * 1536 * 2);  // gate-packed bf16
  __bf16* m0   = (__bf16*)alloc((size_t)16384 * 512 * 2);
  __bf16* r0   = (__bf16*)alloc((size_t)16384 * 512 * 2);
  __bf16* wihp[4]; __bf16* whhp[4]; float* bihp[4]; float* bhhp[4];
  for (int l = 0; l < 4; ++l) {
    wihp[l] = (__bf16*)alloc((size_t)1536 * Kin[l] * 2);
    whhp[l] = (__bf16*)alloc((size_t)1536 * 256 * 2);
    bihp[l] = (float*)alloc(1536 * 4);
    bhhp[l] = (float*)alloc(1536 * 4);
  }
  float* e_g  = (float*)alloc(4096 * 4);
  float* a_g  = (float*)alloc(16384 * 4);
  float* smax = (float*)alloc(16384 * 4);

  for (int l = 0; l < 4; ++l)
    prep_layer<<<1536, 256, 0, stream>>>(w_ih[l], w_hh[l], b_l[l], Kin[l],
                                         wihp[l], whhp[l], bihp[l], bhhp[l]);
  k_dots<<<5120, 256, 0, stream>>>(c, q, Ws, a_g, e_g);
  k_att_main<<<dim3(2, 64), 512, 0, stream>>>(c, q, Ws, a_g, e_g, smax, Gbuf);
  k_att_tail<<<64, 256, 0, stream>>>(c, smax, Gbuf);

  // layer mod0: G(2048) -> m0
  gemm_bt<<<dim3(128, 12), 256, 0, stream>>>(Gbuf, 2560, wihp[0], bihp[0], gi, 2048);
  gru_rec<<<dim3(4, 2), 512, 0, stream>>>(gi, whhp[0], bhhp[0], m0, 512, nullptr);
  // layer mod1: m0(512) -> M (into Gbuf cols 2048:2560)
  gemm_bt<<<dim3(128, 12), 256, 0, stream>>>(m0, 512, wihp[1], bihp[1], gi, 512);
  gru_rec<<<dim3(4, 2), 512, 0, stream>>>(gi, whhp[1], bhhp[1], Gbuf + 2048, 2560, nullptr);
  // layer rep0: [G|M](2560) -> r0
  gemm_bt<<<dim3(128, 12), 256, 0, stream>>>(Gbuf, 2560, wihp[2], bihp[2], gi, 2560);
  gru_rec<<<dim3(4, 2), 512, 0, stream>>>(gi, whhp[2], bhhp[2], r0, 512, nullptr);
  // layer rep1: r0(512) -> final h only
  gemm_bt<<<dim3(128, 12), 256, 0, stream>>>(r0, 512, wihp[3], bihp[3], gi, 512);
  gru_rec<<<dim3(4, 2), 512, 0, stream>>>(gi, whhp[3], bhhp[3], nullptr, 0, (float*)d_out);
}

// Round 3
// 4157.693 us; speedup vs baseline: 1.1980x; 1.0044x over previous
//
#include <hip/hip_runtime.h>

typedef __bf16 bf16x8 __attribute__((ext_vector_type(8)));
typedef float  f32x4  __attribute__((ext_vector_type(4)));

__device__ __forceinline__ float sigm(float x) { return 1.0f / (1.0f + __expf(-x)); }
__device__ __forceinline__ float tanh_(float x) {
  x = fminf(fmaxf(x, -15.0f), 15.0f);
  float e = __expf(-2.0f * x);
  return (1.0f - e) / (1.0f + e);
}
__device__ __forceinline__ float bflo(unsigned u) { return __uint_as_float(u << 16); }
__device__ __forceinline__ float bfhi(unsigned u) { return __uint_as_float(u & 0xffff0000u); }

// ---------------------------------------------------------------------------
// Weight prep. Storage row order r'' (per dir): r'' = w*96 + l15*6 + (dg*3+gt)
// with hidden unit d = w*32 + dg*16 + l15 and source gate row g = gt*256 + d.
// b_hh for r,z gates is folded into bih (GEMM bias); bhh_o keeps raw b_hh.
// ---------------------------------------------------------------------------
__global__ __launch_bounds__(256) void prep_layer(
    const float* __restrict__ Wih, const float* __restrict__ Whh,
    const float* __restrict__ bsrc, int Kin,
    __bf16* __restrict__ wih_o, __bf16* __restrict__ whh_o,
    float* __restrict__ bih_o, float* __restrict__ bhh_o)
{
  int R = blockIdx.x;                 // 0..1535 (dir-major, r''-order)
  int dir = (R >= 768) ? 1 : 0;
  int rp = R - dir * 768;
  int w = rp / 96, rem = rp % 96;
  int l15 = rem / 6, gx = rem % 6;
  int dg = gx / 3, gt = gx % 3;
  int d = w * 32 + dg * 16 + l15;
  int g = gt * 256 + d;
  const float* src = Wih + ((size_t)dir * 768 + g) * Kin;
  __bf16* dst = wih_o + (size_t)R * Kin;
  for (int k = threadIdx.x; k < Kin; k += 256) dst[k] = (__bf16)src[k];
  const float* hs = Whh + ((size_t)dir * 768 + g) * 256;
  __bf16* hd = whh_o + (size_t)R * 256;
  hd[threadIdx.x] = (__bf16)hs[threadIdx.x];
  if (threadIdx.x == 0) {
    float bih = bsrc[(dir * 2 + 0) * 768 + g];
    float bhh = bsrc[(dir * 2 + 1) * 768 + g];
    bih_o[R] = bih + (gt < 2 ? bhh : 0.0f);
    bhh_o[R] = bhh;
  }
}

// ---------------------------------------------------------------------------
// a[b,t] = c[b,t,:]·wc   and   e[b,j] = q[b,j,:]·wq    (one wave per dot)
// ---------------------------------------------------------------------------
__global__ __launch_bounds__(256) void k_dots(
    const float* __restrict__ c, const float* __restrict__ q,
    const float* __restrict__ Ws, float* __restrict__ a_g, float* __restrict__ e_g)
{
  const int wid = blockIdx.x * 4 + (threadIdx.x >> 6);
  const int lane = threadIdx.x & 63;
  const float* x; const float* wv; float* o;
  if (wid < 4096) { x = q + (size_t)wid * 512; wv = Ws + 512; o = e_g + wid; }
  else { int id = wid - 4096; x = c + (size_t)id * 512; wv = Ws; o = a_g + id; }
  float s = 0.f;
  #pragma unroll
  for (int i = 0; i < 8; ++i) s = fmaf(x[lane * 8 + i], wv[lane * 8 + i], s);
  #pragma unroll
  for (int off = 32; off; off >>= 1) s += __shfl_xor(s, off);
  if (lane == 0) *o = s;
}

// ---------------------------------------------------------------------------
// Fused attention main: per (b, t-half).
// ---------------------------------------------------------------------------
__global__ __launch_bounds__(512) void k_att_main(
    const float* __restrict__ c, const float* __restrict__ q,
    const float* __restrict__ Ws, const float* __restrict__ a_g,
    const float* __restrict__ e_g, float* __restrict__ smax_g,
    __bf16* __restrict__ G)
{
  constexpr int QSTR = 513;
  __shared__ float q_s[64 * QSTR];
  __shared__ float c_s[512], cw_s[512], sP[64], e_s[64], sred[512];
  const int b = blockIdx.y, th = blockIdx.x;
  const int tid = threadIdx.x;
  const float* qb = q + (size_t)b * 64 * 512;
  for (int i = tid; i < 64 * 512; i += 512) q_s[(i >> 9) * QSTR + (i & 511)] = qb[i];
  if (tid < 64) e_s[tid] = e_g[b * 64 + tid];
  __syncthreads();
  const int p = tid >> 6;
  const int j = tid & 63;
  for (int tt = 0; tt < 128; ++tt) {
    const int t = th * 128 + tt;
    float cv = c[((size_t)b * 256 + t) * 512 + tid];
    c_s[tid] = cv;
    cw_s[tid] = cv * Ws[1024 + tid];
    __syncthreads();
    {
      const float* qrow = &q_s[j * QSTR + p * 64];
      const float* cw = &cw_s[p * 64];
      float s = 0.f;
      #pragma unroll
      for (int i = 0; i < 64; ++i) s = fmaf(cw[i], qrow[i], s);
      sred[p * 64 + j] = s;
    }
    __syncthreads();
    if (tid < 64) {
      float s = sred[tid] + sred[64 + tid] + sred[128 + tid] + sred[192 + tid]
              + sred[256 + tid] + sred[320 + tid] + sred[384 + tid] + sred[448 + tid];
      s += a_g[b * 256 + t] + e_s[tid];
      float m = s;
      #pragma unroll
      for (int off = 32; off; off >>= 1) m = fmaxf(m, __shfl_xor(m, off));
      float e = __expf(s - m);
      float sum = e;
      #pragma unroll
      for (int off = 32; off; off >>= 1) sum += __shfl_xor(sum, off);
      sP[tid] = e / sum;
      if (tid == 0) smax_g[b * 256 + t] = m;
    }
    __syncthreads();
    {
      float acc = 0.f;
      #pragma unroll 8
      for (int jj = 0; jj < 64; ++jj) acc = fmaf(sP[jj], q_s[jj * QSTR + tid], acc);
      float cval = c_s[tid];
      __bf16* Gr = G + ((size_t)b * 256 + t) * 2560;
      Gr[tid]        = (__bf16)cval;
      Gr[512 + tid]  = (__bf16)acc;
      Gr[1024 + tid] = (__bf16)(cval * acc);
    }
    __syncthreads();
  }
}

// ---------------------------------------------------------------------------
// q2c tail
// ---------------------------------------------------------------------------
__global__ __launch_bounds__(256) void k_att_tail(
    const float* __restrict__ c, const float* __restrict__ smax_g,
    __bf16* __restrict__ G)
{
  __shared__ float w_s[256];
  __shared__ float red[8];
  const int b = blockIdx.x, tid = threadIdx.x;
  const int lane = tid & 63, wv = tid >> 6;
  float v = smax_g[b * 256 + tid];
  float m = v;
  #pragma unroll
  for (int off = 32; off; off >>= 1) m = fmaxf(m, __shfl_xor(m, off));
  if (lane == 0) red[wv] = m;
  __syncthreads();
  m = fmaxf(fmaxf(red[0], red[1]), fmaxf(red[2], red[3]));
  float e = __expf(v - m);
  float s = e;
  #pragma unroll
  for (int off = 32; off; off >>= 1) s += __shfl_xor(s, off);
  if (lane == 0) red[4 + wv] = s;
  __syncthreads();
  s = red[4] + red[5] + red[6] + red[7];
  w_s[tid] = e / s;
  __syncthreads();
  float q0 = 0.f, q1 = 0.f;
  for (int t = 0; t < 256; ++t) {
    const float* cr = c + ((size_t)b * 256 + t) * 512;
    q0 = fmaf(w_s[t], cr[tid], q0);
    q1 = fmaf(w_s[t], cr[tid + 256], q1);
  }
  for (int t = 0; t < 256; ++t) {
    const float* cr = c + ((size_t)b * 256 + t) * 512;
    __bf16* Gr = G + ((size_t)b * 256 + t) * 2560 + 1536;
    Gr[tid]       = (__bf16)(cr[tid] * q0);
    Gr[tid + 256] = (__bf16)(cr[tid + 256] * q1);
  }
}

// ---------------------------------------------------------------------------
// GEMM: C[M,1536] = A[M,K] @ Bw[1536,K]^T + bias, bf16 output.
// ---------------------------------------------------------------------------
__global__ __launch_bounds__(256) void gemm_bt(
    const __bf16* __restrict__ A, int lda,
    const __bf16* __restrict__ Bw, const float* __restrict__ bias,
    __bf16* __restrict__ C, int K)
{
  __shared__ __align__(16) __bf16 As[4096], Bs[4096];
  const int tid = threadIdx.x;
  const int lane = tid & 63, w = tid >> 6;
  const int l15 = lane & 15, lq = lane >> 4;
  const int wm = w >> 1, wn = w & 1;
  const size_t bm = (size_t)blockIdx.x * 128;
  const size_t bn = (size_t)blockIdx.y * 128;
  const int srow = tid >> 2, skg = tid & 3;
  const __bf16* Ag0 = A + (bm + srow) * lda + skg * 8;
  const __bf16* Ag1 = Ag0 + (size_t)64 * lda;
  const __bf16* Bg0 = Bw + (bn + srow) * (size_t)K + skg * 8;
  const __bf16* Bg1 = Bg0 + (size_t)64 * K;
  f32x4 acc[4][4] = {};
  const int nkt = K >> 5;
  for (int kt = 0; kt < nkt; ++kt) {
    const int ko = kt * 32;
    bf16x8 av0 = *(const bf16x8*)(Ag0 + ko);
    bf16x8 av1 = *(const bf16x8*)(Ag1 + ko);
    bf16x8 bv0 = *(const bf16x8*)(Bg0 + ko);
    bf16x8 bv1 = *(const bf16x8*)(Bg1 + ko);
    __syncthreads();
    *(bf16x8*)&As[(skg * 128 + srow) * 8] = av0;
    *(bf16x8*)&As[(skg * 128 + srow + 64) * 8] = av1;
    *(bf16x8*)&Bs[(skg * 128 + srow) * 8] = bv0;
    *(bf16x8*)&Bs[(skg * 128 + srow + 64) * 8] = bv1;
    __syncthreads();
    bf16x8 af[4], bfv[4];
    #pragma unroll
    for (int f = 0; f < 4; ++f) {
      af[f]  = *(const bf16x8*)&As[(lq * 128 + wm * 64 + f * 16 + l15) * 8];
      bfv[f] = *(const bf16x8*)&Bs[(lq * 128 + wn * 64 + f * 16 + l15) * 8];
    }
    #pragma unroll
    for (int fm = 0; fm < 4; ++fm)
      #pragma unroll
      for (int fn = 0; fn < 4; ++fn)
        acc[fm][fn] = __builtin_amdgcn_mfma_f32_16x16x32_bf16(af[fm], bfv[fn], acc[fm][fn], 0, 0, 0);
  }
  float bv[4];
  #pragma unroll
  for (int fn = 0; fn < 4; ++fn) bv[fn] = bias[bn + wn * 64 + fn * 16 + l15];
  #pragma unroll
  for (int fm = 0; fm < 4; ++fm)
    #pragma unroll
    for (int fn = 0; fn < 4; ++fn)
      #pragma unroll
      for (int r = 0; r < 4; ++r) {
        size_t row = bm + wm * 64 + fm * 16 + lq * 4 + r;
        size_t col = bn + wn * 64 + fn * 16 + l15;
        C[row * 1536 + col] = (__bf16)(acc[fm][fn][r] + bv[fn]);
      }
}

// ---------------------------------------------------------------------------
// GRU recurrence v3: exactly 2 waves/EU (256-VGPR budget) so the 192-VGPR
// Whh block stays resident; raw s_barrier (lgkmcnt only — ys stores and gi
// prefetch stay in flight across the barrier); 32-bit offset addressing.
// ---------------------------------------------------------------------------
__global__ __launch_bounds__(512)
__attribute__((amdgpu_waves_per_eu(2, 2)))
void gru_rec(
    const __bf16* __restrict__ gi, const __bf16* __restrict__ whh,
    const float* __restrict__ bhh, __bf16* __restrict__ ys, int ys_stride,
    float* __restrict__ out_final)
{
  constexpr int HSTR = 264;
  __shared__ __align__(16) __bf16 h_lds[2][16 * HSTR];
  const int tid = threadIdx.x;
  const int w = tid >> 6, lane = tid & 63;
  const int l15 = lane & 15, lq = lane >> 4;
  const int dir = blockIdx.y;
  const int b0 = blockIdx.x * 16;

  for (int i = tid; i < 2 * 16 * HSTR; i += 512) (&h_lds[0][0])[i] = (__bf16)0.0f;

  // all 6 weight tiles resident: wreg[dg][gt][ks]  (192 VGPRs)
  bf16x8 wreg[2][3][8];
  #pragma unroll
  for (int dg = 0; dg < 2; ++dg)
    #pragma unroll
    for (int gt = 0; gt < 3; ++gt) {
      const __bf16* wp = whh + ((size_t)dir * 768 + w * 96 + l15 * 6 + dg * 3 + gt) * 256 + lq * 8;
      #pragma unroll
      for (int ks = 0; ks < 8; ++ks)
        wreg[dg][gt][ks] = *(const bf16x8*)(wp + ks * 32);
    }
  float bhn0 = bhh[dir * 768 + w * 96 + l15 * 6 + 2];
  float bhn1 = bhh[dir * 768 + w * 96 + l15 * 6 + 5];

  // 32-bit element offsets (SGPR base + VGPR voffset addressing)
  const unsigned gofs = (unsigned)(b0 + lq * 4) * (256u * 1536u) + (unsigned)dir * 768u
                      + (unsigned)w * 96u + (unsigned)l15 * 6u;
  const unsigned yofs = (unsigned)(b0 + lq * 4) * (256u * (unsigned)ys_stride)
                      + (unsigned)dir * 256u + (unsigned)w * 32u + (unsigned)l15;

  float hprev[2][4] = {};
  int cur = 0;
  __syncthreads();

  for (int s = 0; s < 256; ++s) {
    const int t = dir ? (255 - s) : s;
    // gi prefetch: 3 dwords x 4 batches, consumed after the MFMAs
    unsigned gw[4][3];
    const unsigned gbase = gofs + (unsigned)t * 1536u;
    #pragma unroll
    for (int r = 0; r < 4; ++r) {
      const unsigned* p = (const unsigned*)(gi + (gbase + (unsigned)r * (256u * 1536u)));
      gw[r][0] = p[0]; gw[r][1] = p[1]; gw[r][2] = p[2];
    }
    // gh = h @ Whh'^T (weights in registers)
    f32x4 acc[2][3] = {};
    const __bf16* hb_ = &h_lds[cur][l15 * HSTR + lq * 8];
    #pragma unroll
    for (int ks = 0; ks < 8; ++ks) {
      bf16x8 af = *(const bf16x8*)(hb_ + ks * 32);
      #pragma unroll
      for (int dg = 0; dg < 2; ++dg)
        #pragma unroll
        for (int gt = 0; gt < 3; ++gt)
          acc[dg][gt] = __builtin_amdgcn_mfma_f32_16x16x32_bf16(af, wreg[dg][gt][ks], acc[dg][gt], 0, 0, 0);
    }
    // gates + h update
    #pragma unroll
    for (int dg = 0; dg < 2; ++dg)
      #pragma unroll
      for (int r = 0; r < 4; ++r) {
        float ir, iz, in_;
        if (dg == 0) { ir = bflo(gw[r][0]); iz = bfhi(gw[r][0]); in_ = bflo(gw[r][1]); }
        else         { ir = bfhi(gw[r][1]); iz = bflo(gw[r][2]); in_ = bfhi(gw[r][2]); }
        float bn_ = dg ? bhn1 : bhn0;
        float rg = sigm(ir + acc[dg][0][r]);
        float zg = sigm(iz + acc[dg][1][r]);
        float ng = tanh_(in_ + rg * (acc[dg][2][r] + bn_));
        float h = ng + zg * (hprev[dg][r] - ng);
        hprev[dg][r] = h;
        h_lds[cur ^ 1][(lq * 4 + r) * HSTR + w * 32 + dg * 16 + l15] = (__bf16)h;
        if (ys) ys[yofs + (unsigned)(r * 256 + t) * (unsigned)ys_stride + dg * 16] = (__bf16)h;
      }
    // raw barrier: order LDS only; global ys stores / gi loads stay in flight
    asm volatile("s_waitcnt lgkmcnt(0)\n\ts_barrier" ::: "memory");
    cur ^= 1;
  }
  if (!ys) {
    #pragma unroll
    for (int dg = 0; dg < 2; ++dg)
      #pragma unroll
      for (int r = 0; r < 4; ++r)
        out_final[(size_t)(b0 + lq * 4 + r) * 512 + (dir ? 0 : 256) + w * 32 + dg * 16 + l15]
            = hprev[dg][r];
  }
}

// ---------------------------------------------------------------------------
extern "C" void kernel_launch(void* const* d_in, const int* in_sizes, int n_in,
                              void* d_out, int out_size, void* d_ws, size_t ws_size,
                              hipStream_t stream) {
  (void)in_sizes; (void)n_in; (void)out_size; (void)ws_size;
  const float* c  = (const float*)d_in[0];
  const float* q  = (const float*)d_in[1];
  const float* Ws = (const float*)d_in[4];
  const float* w_ih[4] = { (const float*)d_in[5], (const float*)d_in[8],
                           (const float*)d_in[11], (const float*)d_in[14] };
  const float* w_hh[4] = { (const float*)d_in[6], (const float*)d_in[9],
                           (const float*)d_in[12], (const float*)d_in[15] };
  const float* b_l[4]  = { (const float*)d_in[7], (const float*)d_in[10],
                           (const float*)d_in[13], (const float*)d_in[16] };
  const int Kin[4] = {2048, 512, 2560, 512};

  char* ws = (char*)d_ws;
  size_t off = 0;
  auto alloc = [&](size_t bytes) -> void* {
    void* p = ws + off; off += (bytes + 255) & ~(size_t)255; return p;
  };
  __bf16* Gbuf = (__bf16*)alloc((size_t)16384 * 2560 * 2);  // [G | M] bf16
  __bf16* gi   = (__bf16*)alloc((size_t)16384 * 1536 * 2);  // gate-packed bf16
  __bf16* m0   = (__bf16*)alloc((size_t)16384 * 512 * 2);
  __bf16* r0   = (__bf16*)alloc((size_t)16384 * 512 * 2);
  __bf16* wihp[4]; __bf16* whhp[4]; float* bihp[4]; float* bhhp[4];
  for (int l = 0; l < 4; ++l) {
    wihp[l] = (__bf16*)alloc((size_t)1536 * Kin[l] * 2);
    whhp[l] = (__bf16*)alloc((size_t)1536 * 256 * 2);
    bihp[l] = (float*)alloc(1536 * 4);
    bhhp[l] = (float*)alloc(1536 * 4);
  }
  float* e_g  = (float*)alloc(4096 * 4);
  float* a_g  = (float*)alloc(16384 * 4);
  float* smax = (float*)alloc(16384 * 4);

  for (int l = 0; l < 4; ++l)
    prep_layer<<<1536, 256, 0, stream>>>(w_ih[l], w_hh[l], b_l[l], Kin[l],
                                         wihp[l], whhp[l], bihp[l], bhhp[l]);
  k_dots<<<5120, 256, 0, stream>>>(c, q, Ws, a_g, e_g);
  k_att_main<<<dim3(2, 64), 512, 0, stream>>>(c, q, Ws, a_g, e_g, smax, Gbuf);
  k_att_tail<<<64, 256, 0, stream>>>(c, smax, Gbuf);

  // layer mod0: G(2048) -> m0
  gemm_bt<<<dim3(128, 12), 256, 0, stream>>>(Gbuf, 2560, wihp[0], bihp[0], gi, 2048);
  gru_rec<<<dim3(4, 2), 512, 0, stream>>>(gi, whhp[0], bhhp[0], m0, 512, nullptr);
  // layer mod1: m0(512) -> M (into Gbuf cols 2048:2560)
  gemm_bt<<<dim3(128, 12), 256, 0, stream>>>(m0, 512, wihp[1], bihp[1], gi, 512);
  gru_rec<<<dim3(4, 2), 512, 0, stream>>>(gi, whhp[1], bhhp[1], Gbuf + 2048, 2560, nullptr);
  // layer rep0: [G|M](2560) -> r0
  gemm_bt<<<dim3(128, 12), 256, 0, stream>>>(Gbuf, 2560, wihp[2], bihp[2], gi, 2560);
  gru_rec<<<dim3(4, 2), 512, 0, stream>>>(gi, whhp[2], bhhp[2], r0, 512, nullptr);
  // layer rep1: r0(512) -> final h only
  gemm_bt<<<dim3(128, 12), 256, 0, stream>>>(r0, 512, wihp[3], bihp[3], gi, 512);
  gru_rec<<<dim3(4, 2), 512, 0, stream>>>(gi, whhp[3], bhhp[3], nullptr, 0, (float*)d_out);
}

// Round 4
// 3866.092 us; speedup vs baseline: 1.2883x; 1.0754x over previous
//
#include <hip/hip_runtime.h>

typedef __bf16 bf16x8 __attribute__((ext_vector_type(8)));
typedef float  f32x4  __attribute__((ext_vector_type(4)));

__device__ __forceinline__ float sigm(float x) { return 1.0f / (1.0f + __expf(-x)); }
__device__ __forceinline__ float tanh_(float x) {
  x = fminf(fmaxf(x, -15.0f), 15.0f);
  float e = __expf(-2.0f * x);
  return (1.0f - e) / (1.0f + e);
}
__device__ __forceinline__ float bflo(unsigned u) { return __uint_as_float(u << 16); }
__device__ __forceinline__ float bfhi(unsigned u) { return __uint_as_float(u & 0xffff0000u); }

// ---------------------------------------------------------------------------
// Weight prep. wstream: fragment-major, per-wave-coalesced weight layout:
//   chunk c = ks*6 + dg*3 + gt  (ks=k/32 slice, dg=hid-16-group, gt=gate)
//   flat bf16 idx = (((dir*8 + w)*48 + c)*64 + (lq*16 + l15))*8 + e
//   value = Whh[dir][g = gt*256 + w*32 + dg*16 + l15][ks*32 + lq*8 + e]
// A weight-load instr in gru_rec then reads one contiguous 1KB block.
// Wih rows reordered to r'' = w*96 + l15*6 + dg*3 + gt (gate-packed gi).
// b_hh for r,z folded into GEMM bias; bhh_o keeps raw b_hh (n-gate use).
// ---------------------------------------------------------------------------
__global__ __launch_bounds__(256) void prep_layer(
    const float* __restrict__ Wih, const float* __restrict__ Whh,
    const float* __restrict__ bsrc, int Kin,
    __bf16* __restrict__ wih_o, __bf16* __restrict__ wstream_o,
    float* __restrict__ bih_o, float* __restrict__ bhh_o)
{
  int R = blockIdx.x;                 // 0..1535 (dir-major, r''-order)
  int dir = (R >= 768) ? 1 : 0;
  int rp = R - dir * 768;
  int w = rp / 96, rem = rp % 96;
  int l15 = rem / 6, gx = rem % 6;
  int dg = gx / 3, gt = gx % 3;
  int d = w * 32 + dg * 16 + l15;
  int g = gt * 256 + d;
  const float* src = Wih + ((size_t)dir * 768 + g) * Kin;
  __bf16* dst = wih_o + (size_t)R * Kin;
  for (int k = threadIdx.x; k < Kin; k += 256) dst[k] = (__bf16)src[k];
  {
    int k = threadIdx.x;              // 0..255
    int ks = k >> 5, lq = (k >> 3) & 3, e = k & 7;
    int c = ks * 6 + dg * 3 + gt;
    size_t di = ((((size_t)dir * 8 + w) * 48 + c) * 64 + (lq * 16 + l15)) * 8 + e;
    wstream_o[di] = (__bf16)Whh[((size_t)dir * 768 + g) * 256 + k];
  }
  if (threadIdx.x == 0) {
    float bih = bsrc[(dir * 2 + 0) * 768 + g];
    float bhh = bsrc[(dir * 2 + 1) * 768 + g];
    bih_o[R] = bih + (gt < 2 ? bhh : 0.0f);
    bhh_o[R] = bhh;
  }
}

// ---------------------------------------------------------------------------
// a[b,t] = c[b,t,:]·wc   and   e[b,j] = q[b,j,:]·wq    (one wave per dot)
// ---------------------------------------------------------------------------
__global__ __launch_bounds__(256) void k_dots(
    const float* __restrict__ c, const float* __restrict__ q,
    const float* __restrict__ Ws, float* __restrict__ a_g, float* __restrict__ e_g)
{
  const int wid = blockIdx.x * 4 + (threadIdx.x >> 6);
  const int lane = threadIdx.x & 63;
  const float* x; const float* wv; float* o;
  if (wid < 4096) { x = q + (size_t)wid * 512; wv = Ws + 512; o = e_g + wid; }
  else { int id = wid - 4096; x = c + (size_t)id * 512; wv = Ws; o = a_g + id; }
  float s = 0.f;
  #pragma unroll
  for (int i = 0; i < 8; ++i) s = fmaf(x[lane * 8 + i], wv[lane * 8 + i], s);
  #pragma unroll
  for (int off = 32; off; off >>= 1) s += __shfl_xor(s, off);
  if (lane == 0) *o = s;
}

// ---------------------------------------------------------------------------
// Fused attention main: per (b, t-half).
// ---------------------------------------------------------------------------
__global__ __launch_bounds__(512) void k_att_main(
    const float* __restrict__ c, const float* __restrict__ q,
    const float* __restrict__ Ws, const float* __restrict__ a_g,
    const float* __restrict__ e_g, float* __restrict__ smax_g,
    __bf16* __restrict__ G)
{
  constexpr int QSTR = 513;
  __shared__ float q_s[64 * QSTR];
  __shared__ float c_s[512], cw_s[512], sP[64], e_s[64], sred[512];
  const int b = blockIdx.y, th = blockIdx.x;
  const int tid = threadIdx.x;
  const float* qb = q + (size_t)b * 64 * 512;
  for (int i = tid; i < 64 * 512; i += 512) q_s[(i >> 9) * QSTR + (i & 511)] = qb[i];
  if (tid < 64) e_s[tid] = e_g[b * 64 + tid];
  __syncthreads();
  const int p = tid >> 6;
  const int j = tid & 63;
  for (int tt = 0; tt < 128; ++tt) {
    const int t = th * 128 + tt;
    float cv = c[((size_t)b * 256 + t) * 512 + tid];
    c_s[tid] = cv;
    cw_s[tid] = cv * Ws[1024 + tid];
    __syncthreads();
    {
      const float* qrow = &q_s[j * QSTR + p * 64];
      const float* cw = &cw_s[p * 64];
      float s = 0.f;
      #pragma unroll
      for (int i = 0; i < 64; ++i) s = fmaf(cw[i], qrow[i], s);
      sred[p * 64 + j] = s;
    }
    __syncthreads();
    if (tid < 64) {
      float s = sred[tid] + sred[64 + tid] + sred[128 + tid] + sred[192 + tid]
              + sred[256 + tid] + sred[320 + tid] + sred[384 + tid] + sred[448 + tid];
      s += a_g[b * 256 + t] + e_s[tid];
      float m = s;
      #pragma unroll
      for (int off = 32; off; off >>= 1) m = fmaxf(m, __shfl_xor(m, off));
      float e = __expf(s - m);
      float sum = e;
      #pragma unroll
      for (int off = 32; off; off >>= 1) sum += __shfl_xor(sum, off);
      sP[tid] = e / sum;
      if (tid == 0) smax_g[b * 256 + t] = m;
    }
    __syncthreads();
    {
      float acc = 0.f;
      #pragma unroll 8
      for (int jj = 0; jj < 64; ++jj) acc = fmaf(sP[jj], q_s[jj * QSTR + tid], acc);
      float cval = c_s[tid];
      __bf16* Gr = G + ((size_t)b * 256 + t) * 2560;
      Gr[tid]        = (__bf16)cval;
      Gr[512 + tid]  = (__bf16)acc;
      Gr[1024 + tid] = (__bf16)(cval * acc);
    }
    __syncthreads();
  }
}

// ---------------------------------------------------------------------------
// q2c tail
// ---------------------------------------------------------------------------
__global__ __launch_bounds__(256) void k_att_tail(
    const float* __restrict__ c, const float* __restrict__ smax_g,
    __bf16* __restrict__ G)
{
  __shared__ float w_s[256];
  __shared__ float red[8];
  const int b = blockIdx.x, tid = threadIdx.x;
  const int lane = tid & 63, wv = tid >> 6;
  float v = smax_g[b * 256 + tid];
  float m = v;
  #pragma unroll
  for (int off = 32; off; off >>= 1) m = fmaxf(m, __shfl_xor(m, off));
  if (lane == 0) red[wv] = m;
  __syncthreads();
  m = fmaxf(fmaxf(red[0], red[1]), fmaxf(red[2], red[3]));
  float e = __expf(v - m);
  float s = e;
  #pragma unroll
  for (int off = 32; off; off >>= 1) s += __shfl_xor(s, off);
  if (lane == 0) red[4 + wv] = s;
  __syncthreads();
  s = red[4] + red[5] + red[6] + red[7];
  w_s[tid] = e / s;
  __syncthreads();
  float q0 = 0.f, q1 = 0.f;
  for (int t = 0; t < 256; ++t) {
    const float* cr = c + ((size_t)b * 256 + t) * 512;
    q0 = fmaf(w_s[t], cr[tid], q0);
    q1 = fmaf(w_s[t], cr[tid + 256], q1);
  }
  for (int t = 0; t < 256; ++t) {
    const float* cr = c + ((size_t)b * 256 + t) * 512;
    __bf16* Gr = G + ((size_t)b * 256 + t) * 2560 + 1536;
    Gr[tid]       = (__bf16)(cr[tid] * q0);
    Gr[tid + 256] = (__bf16)(cr[tid + 256] * q1);
  }
}

// ---------------------------------------------------------------------------
// GEMM: C[M,1536] = A[M,K] @ Bw[1536,K]^T + bias, bf16 output.
// ---------------------------------------------------------------------------
__global__ __launch_bounds__(256) void gemm_bt(
    const __bf16* __restrict__ A, int lda,
    const __bf16* __restrict__ Bw, const float* __restrict__ bias,
    __bf16* __restrict__ C, int K)
{
  __shared__ __align__(16) __bf16 As[4096], Bs[4096];
  const int tid = threadIdx.x;
  const int lane = tid & 63, w = tid >> 6;
  const int l15 = lane & 15, lq = lane >> 4;
  const int wm = w >> 1, wn = w & 1;
  const size_t bm = (size_t)blockIdx.x * 128;
  const size_t bn = (size_t)blockIdx.y * 128;
  const int srow = tid >> 2, skg = tid & 3;
  const __bf16* Ag0 = A + (bm + srow) * lda + skg * 8;
  const __bf16* Ag1 = Ag0 + (size_t)64 * lda;
  const __bf16* Bg0 = Bw + (bn + srow) * (size_t)K + skg * 8;
  const __bf16* Bg1 = Bg0 + (size_t)64 * K;
  f32x4 acc[4][4] = {};
  const int nkt = K >> 5;
  for (int kt = 0; kt < nkt; ++kt) {
    const int ko = kt * 32;
    bf16x8 av0 = *(const bf16x8*)(Ag0 + ko);
    bf16x8 av1 = *(const bf16x8*)(Ag1 + ko);
    bf16x8 bv0 = *(const bf16x8*)(Bg0 + ko);
    bf16x8 bv1 = *(const bf16x8*)(Bg1 + ko);
    __syncthreads();
    *(bf16x8*)&As[(skg * 128 + srow) * 8] = av0;
    *(bf16x8*)&As[(skg * 128 + srow + 64) * 8] = av1;
    *(bf16x8*)&Bs[(skg * 128 + srow) * 8] = bv0;
    *(bf16x8*)&Bs[(skg * 128 + srow + 64) * 8] = bv1;
    __syncthreads();
    bf16x8 af[4], bfv[4];
    #pragma unroll
    for (int f = 0; f < 4; ++f) {
      af[f]  = *(const bf16x8*)&As[(lq * 128 + wm * 64 + f * 16 + l15) * 8];
      bfv[f] = *(const bf16x8*)&Bs[(lq * 128 + wn * 64 + f * 16 + l15) * 8];
    }
    #pragma unroll
    for (int fm = 0; fm < 4; ++fm)
      #pragma unroll
      for (int fn = 0; fn < 4; ++fn)
        acc[fm][fn] = __builtin_amdgcn_mfma_f32_16x16x32_bf16(af[fm], bfv[fn], acc[fm][fn], 0, 0, 0);
  }
  float bv[4];
  #pragma unroll
  for (int fn = 0; fn < 4; ++fn) bv[fn] = bias[bn + wn * 64 + fn * 16 + l15];
  #pragma unroll
  for (int fm = 0; fm < 4; ++fm)
    #pragma unroll
    for (int fn = 0; fn < 4; ++fn)
      #pragma unroll
      for (int r = 0; r < 4; ++r) {
        size_t row = bm + wm * 64 + fm * 16 + lq * 4 + r;
        size_t col = bn + wn * 64 + fn * 16 + l15;
        C[row * 1536 + col] = (__bf16)(acc[fm][fn][r] + bv[fn]);
      }
}

// ---------------------------------------------------------------------------
// GRU recurrence v4: coalesced fragment-major weight stream; first 16 chunks
// per wave (128KB/WG) cached in LDS before the loop, remaining 32 chunks
// (256KB/CU/step) streamed from L2 as contiguous 1KB loads. Dynamic LDS
// 148KB. Raw lgkm-only barrier; double-buffered h.
// ---------------------------------------------------------------------------
#define GRU_LDS_BYTES (131072 + 16896)
__global__ __launch_bounds__(512) void gru_rec(
    const __bf16* __restrict__ gi, const __bf16* __restrict__ wstream,
    const float* __restrict__ bhh, __bf16* __restrict__ ys, int ys_stride,
    float* __restrict__ out_final)
{
  constexpr int HSTR = 264;
  extern __shared__ __align__(16) char smem[];
  __bf16* wlds = (__bf16*)smem;                       // 65536 bf16 = 128KB
  __bf16* hl   = (__bf16*)(smem + 131072);            // 2 * 16*HSTR bf16
  const int tid = threadIdx.x;
  const int w = tid >> 6, lane = tid & 63;
  const int l15 = lane & 15, lq = lane >> 4;
  const int dir = blockIdx.y;
  const int b0 = blockIdx.x * 16;

  for (int i = tid; i < 2 * 16 * HSTR; i += 512) hl[i] = (__bf16)0.0f;

  const __bf16* wbase = wstream + ((size_t)(dir * 8 + w)) * (48 * 64 * 8);
  // cache chunks 0..15 (16KB per wave, own-wave use only)
  #pragma unroll
  for (int c0 = 0; c0 < 16; ++c0)
    *(bf16x8*)&wlds[((w * 16 + c0) * 64 + lane) * 8] =
        *(const bf16x8*)(wbase + ((size_t)(c0 * 64 + lane)) * 8);

  float bhn0 = bhh[dir * 768 + w * 96 + l15 * 6 + 2];
  float bhn1 = bhh[dir * 768 + w * 96 + l15 * 6 + 5];

  const unsigned gofs = (unsigned)(b0 + lq * 4) * (256u * 1536u) + (unsigned)dir * 768u
                      + (unsigned)w * 96u + (unsigned)l15 * 6u;
  const unsigned yofs = (unsigned)(b0 + lq * 4) * (256u * (unsigned)ys_stride)
                      + (unsigned)dir * 256u + (unsigned)w * 32u + (unsigned)l15;

  float hprev[2][4] = {};
  int cur = 0;
  __syncthreads();

  for (int s = 0; s < 256; ++s) {
    const int t = dir ? (255 - s) : s;
    // gi prefetch: 3 dwords x 4 batches
    unsigned gw[4][3];
    const unsigned gbase = gofs + (unsigned)t * 1536u;
    #pragma unroll
    for (int r = 0; r < 4; ++r) {
      const unsigned* p = (const unsigned*)(gi + (gbase + (unsigned)r * (256u * 1536u)));
      gw[r][0] = p[0]; gw[r][1] = p[1]; gw[r][2] = p[2];
    }
    // gh = h @ Whh'^T; chunks c<16 from LDS, rest streamed coalesced from L2
    f32x4 acc[2][3] = {};
    const __bf16* hb_ = &hl[cur * (16 * HSTR) + l15 * HSTR + lq * 8];
    #pragma unroll
    for (int ks = 0; ks < 8; ++ks) {
      bf16x8 af = *(const bf16x8*)(hb_ + ks * 32);
      #pragma unroll
      for (int j = 0; j < 6; ++j) {
        const int c = ks * 6 + j;
        bf16x8 wv;
        if (c < 16) wv = *(const bf16x8*)&wlds[((w * 16 + c) * 64 + lane) * 8];
        else        wv = *(const bf16x8*)(wbase + ((size_t)(c * 64 + lane)) * 8);
        acc[j / 3][j % 3] = __builtin_amdgcn_mfma_f32_16x16x32_bf16(af, wv, acc[j / 3][j % 3], 0, 0, 0);
      }
    }
    // gates + h update
    #pragma unroll
    for (int dg = 0; dg < 2; ++dg)
      #pragma unroll
      for (int r = 0; r < 4; ++r) {
        float ir, iz, in_;
        if (dg == 0) { ir = bflo(gw[r][0]); iz = bfhi(gw[r][0]); in_ = bflo(gw[r][1]); }
        else         { ir = bfhi(gw[r][1]); iz = bflo(gw[r][2]); in_ = bfhi(gw[r][2]); }
        float bn_ = dg ? bhn1 : bhn0;
        float rg = sigm(ir + acc[dg][0][r]);
        float zg = sigm(iz + acc[dg][1][r]);
        float ng = tanh_(in_ + rg * (acc[dg][2][r] + bn_));
        float h = ng + zg * (hprev[dg][r] - ng);
        hprev[dg][r] = h;
        hl[(cur ^ 1) * (16 * HSTR) + (lq * 4 + r) * HSTR + w * 32 + dg * 16 + l15] = (__bf16)h;
        if (ys) ys[yofs + (unsigned)(r * 256 + t) * (unsigned)ys_stride + dg * 16] = (__bf16)h;
      }
    // raw barrier: order LDS only; global ys stores / weight loads stay in flight
    asm volatile("s_waitcnt lgkmcnt(0)\n\ts_barrier" ::: "memory");
    cur ^= 1;
  }
  if (!ys) {
    #pragma unroll
    for (int dg = 0; dg < 2; ++dg)
      #pragma unroll
      for (int r = 0; r < 4; ++r)
        out_final[(size_t)(b0 + lq * 4 + r) * 512 + (dir ? 0 : 256) + w * 32 + dg * 16 + l15]
            = hprev[dg][r];
  }
}

// ---------------------------------------------------------------------------
extern "C" void kernel_launch(void* const* d_in, const int* in_sizes, int n_in,
                              void* d_out, int out_size, void* d_ws, size_t ws_size,
                              hipStream_t stream) {
  (void)in_sizes; (void)n_in; (void)out_size; (void)ws_size;
  const float* c  = (const float*)d_in[0];
  const float* q  = (const float*)d_in[1];
  const float* Ws = (const float*)d_in[4];
  const float* w_ih[4] = { (const float*)d_in[5], (const float*)d_in[8],
                           (const float*)d_in[11], (const float*)d_in[14] };
  const float* w_hh[4] = { (const float*)d_in[6], (const float*)d_in[9],
                           (const float*)d_in[12], (const float*)d_in[15] };
  const float* b_l[4]  = { (const float*)d_in[7], (const float*)d_in[10],
                           (const float*)d_in[13], (const float*)d_in[16] };
  const int Kin[4] = {2048, 512, 2560, 512};

  static int lds_set = 0;
  if (!lds_set) {
    hipFuncSetAttribute((const void*)gru_rec,
                        hipFuncAttributeMaxDynamicSharedMemorySize, GRU_LDS_BYTES);
    lds_set = 1;
  }

  char* ws = (char*)d_ws;
  size_t off = 0;
  auto alloc = [&](size_t bytes) -> void* {
    void* p = ws + off; off += (bytes + 255) & ~(size_t)255; return p;
  };
  __bf16* Gbuf = (__bf16*)alloc((size_t)16384 * 2560 * 2);  // [G | M] bf16
  __bf16* gi   = (__bf16*)alloc((size_t)16384 * 1536 * 2);  // gate-packed bf16
  __bf16* m0   = (__bf16*)alloc((size_t)16384 * 512 * 2);
  __bf16* r0   = (__bf16*)alloc((size_t)16384 * 512 * 2);
  __bf16* wihp[4]; __bf16* wstr[4]; float* bihp[4]; float* bhhp[4];
  for (int l = 0; l < 4; ++l) {
    wihp[l] = (__bf16*)alloc((size_t)1536 * Kin[l] * 2);
    wstr[l] = (__bf16*)alloc((size_t)1536 * 256 * 2);   // fragment-major stream
    bihp[l] = (float*)alloc(1536 * 4);
    bhhp[l] = (float*)alloc(1536 * 4);
  }
  float* e_g  = (float*)alloc(4096 * 4);
  float* a_g  = (float*)alloc(16384 * 4);
  float* smax = (float*)alloc(16384 * 4);

  for (int l = 0; l < 4; ++l)
    prep_layer<<<1536, 256, 0, stream>>>(w_ih[l], w_hh[l], b_l[l], Kin[l],
                                         wihp[l], wstr[l], bihp[l], bhhp[l]);
  k_dots<<<5120, 256, 0, stream>>>(c, q, Ws, a_g, e_g);
  k_att_main<<<dim3(2, 64), 512, 0, stream>>>(c, q, Ws, a_g, e_g, smax, Gbuf);
  k_att_tail<<<64, 256, 0, stream>>>(c, smax, Gbuf);

  // layer mod0: G(2048) -> m0
  gemm_bt<<<dim3(128, 12), 256, 0, stream>>>(Gbuf, 2560, wihp[0], bihp[0], gi, 2048);
  gru_rec<<<dim3(4, 2), 512, GRU_LDS_BYTES, stream>>>(gi, wstr[0], bhhp[0], m0, 512, nullptr);
  // layer mod1: m0(512) -> M (into Gbuf cols 2048:2560)
  gemm_bt<<<dim3(128, 12), 256, 0, stream>>>(m0, 512, wihp[1], bihp[1], gi, 512);
  gru_rec<<<dim3(4, 2), 512, GRU_LDS_BYTES, stream>>>(gi, wstr[1], bhhp[1], Gbuf + 2048, 2560, nullptr);
  // layer rep0: [G|M](2560) -> r0
  gemm_bt<<<dim3(128, 12), 256, 0, stream>>>(Gbuf, 2560, wihp[2], bihp[2], gi, 2560);
  gru_rec<<<dim3(4, 2), 512, GRU_LDS_BYTES, stream>>>(gi, wstr[2], bhhp[2], r0, 512, nullptr);
  // layer rep1: r0(512) -> final h only
  gemm_bt<<<dim3(128, 12), 256, 0, stream>>>(r0, 512, wihp[3], bihp[3], gi, 512);
  gru_rec<<<dim3(4, 2), 512, GRU_LDS_BYTES, stream>>>(gi, wstr[3], bhhp[3], nullptr, 0, (float*)d_out);
}

// Round 5
// 2803.026 us; speedup vs baseline: 1.7769x; 1.3793x over previous
//
#include <hip/hip_runtime.h>

typedef __bf16 bf16x8 __attribute__((ext_vector_type(8)));
typedef float  f32x4  __attribute__((ext_vector_type(4)));

__device__ __forceinline__ float rcp_(float x) { return __builtin_amdgcn_rcpf(x); }
__device__ __forceinline__ float bflo(unsigned u) { return __uint_as_float(u << 16); }
__device__ __forceinline__ float bfhi(unsigned u) { return __uint_as_float(u & 0xffff0000u); }

// ---------------------------------------------------------------------------
// Weight prep. wstream: fragment-major, per-wave-coalesced weight layout:
//   chunk c = ks*6 + dg*3 + gt ; flat idx (((dir*8+w)*48+c)*64 + lane)*8 + e
// Wih rows reordered to r'' = w*96 + l15*6 + dg*3 + gt (gate-packed gi).
// b_hh for r,z folded into GEMM bias; bhh_o keeps raw b_hh (n-gate use).
// ---------------------------------------------------------------------------
__global__ __launch_bounds__(256) void prep_layer(
    const float* __restrict__ Wih, const float* __restrict__ Whh,
    const float* __restrict__ bsrc, int Kin,
    __bf16* __restrict__ wih_o, __bf16* __restrict__ wstream_o,
    float* __restrict__ bih_o, float* __restrict__ bhh_o)
{
  int R = blockIdx.x;                 // 0..1535 (dir-major, r''-order)
  int dir = (R >= 768) ? 1 : 0;
  int rp = R - dir * 768;
  int w = rp / 96, rem = rp % 96;
  int l15 = rem / 6, gx = rem % 6;
  int dg = gx / 3, gt = gx % 3;
  int d = w * 32 + dg * 16 + l15;
  int g = gt * 256 + d;
  const float* src = Wih + ((size_t)dir * 768 + g) * Kin;
  __bf16* dst = wih_o + (size_t)R * Kin;
  for (int k = threadIdx.x; k < Kin; k += 256) dst[k] = (__bf16)src[k];
  {
    int k = threadIdx.x;              // 0..255
    int ks = k >> 5, lq = (k >> 3) & 3, e = k & 7;
    int c = ks * 6 + dg * 3 + gt;
    size_t di = ((((size_t)dir * 8 + w) * 48 + c) * 64 + (lq * 16 + l15)) * 8 + e;
    wstream_o[di] = (__bf16)Whh[((size_t)dir * 768 + g) * 256 + k];
  }
  if (threadIdx.x == 0) {
    float bih = bsrc[(dir * 2 + 0) * 768 + g];
    float bhh = bsrc[(dir * 2 + 1) * 768 + g];
    bih_o[R] = bih + (gt < 2 ? bhh : 0.0f);
    bhh_o[R] = bhh;
  }
}

// ---------------------------------------------------------------------------
// a[b,t] = c[b,t,:]·wc   and   e[b,j] = q[b,j,:]·wq    (one wave per dot)
// ---------------------------------------------------------------------------
__global__ __launch_bounds__(256) void k_dots(
    const float* __restrict__ c, const float* __restrict__ q,
    const float* __restrict__ Ws, float* __restrict__ a_g, float* __restrict__ e_g)
{
  const int wid = blockIdx.x * 4 + (threadIdx.x >> 6);
  const int lane = threadIdx.x & 63;
  const float* x; const float* wv; float* o;
  if (wid < 4096) { x = q + (size_t)wid * 512; wv = Ws + 512; o = e_g + wid; }
  else { int id = wid - 4096; x = c + (size_t)id * 512; wv = Ws; o = a_g + id; }
  float s = 0.f;
  #pragma unroll
  for (int i = 0; i < 8; ++i) s = fmaf(x[lane * 8 + i], wv[lane * 8 + i], s);
  #pragma unroll
  for (int off = 32; off; off >>= 1) s += __shfl_xor(s, off);
  if (lane == 0) *o = s;
}

// ---------------------------------------------------------------------------
// Fused attention main: per (b, t-half).
// ---------------------------------------------------------------------------
__global__ __launch_bounds__(512) void k_att_main(
    const float* __restrict__ c, const float* __restrict__ q,
    const float* __restrict__ Ws, const float* __restrict__ a_g,
    const float* __restrict__ e_g, float* __restrict__ smax_g,
    __bf16* __restrict__ G)
{
  constexpr int QSTR = 513;
  __shared__ float q_s[64 * QSTR];
  __shared__ float c_s[512], cw_s[512], sP[64], e_s[64], sred[512];
  const int b = blockIdx.y, th = blockIdx.x;
  const int tid = threadIdx.x;
  const float* qb = q + (size_t)b * 64 * 512;
  for (int i = tid; i < 64 * 512; i += 512) q_s[(i >> 9) * QSTR + (i & 511)] = qb[i];
  if (tid < 64) e_s[tid] = e_g[b * 64 + tid];
  __syncthreads();
  const int p = tid >> 6;
  const int j = tid & 63;
  for (int tt = 0; tt < 128; ++tt) {
    const int t = th * 128 + tt;
    float cv = c[((size_t)b * 256 + t) * 512 + tid];
    c_s[tid] = cv;
    cw_s[tid] = cv * Ws[1024 + tid];
    __syncthreads();
    {
      const float* qrow = &q_s[j * QSTR + p * 64];
      const float* cw = &cw_s[p * 64];
      float s = 0.f;
      #pragma unroll
      for (int i = 0; i < 64; ++i) s = fmaf(cw[i], qrow[i], s);
      sred[p * 64 + j] = s;
    }
    __syncthreads();
    if (tid < 64) {
      float s = sred[tid] + sred[64 + tid] + sred[128 + tid] + sred[192 + tid]
              + sred[256 + tid] + sred[320 + tid] + sred[384 + tid] + sred[448 + tid];
      s += a_g[b * 256 + t] + e_s[tid];
      float m = s;
      #pragma unroll
      for (int off = 32; off; off >>= 1) m = fmaxf(m, __shfl_xor(m, off));
      float e = __expf(s - m);
      float sum = e;
      #pragma unroll
      for (int off = 32; off; off >>= 1) sum += __shfl_xor(sum, off);
      sP[tid] = e / sum;
      if (tid == 0) smax_g[b * 256 + t] = m;
    }
    __syncthreads();
    {
      float acc = 0.f;
      #pragma unroll 8
      for (int jj = 0; jj < 64; ++jj) acc = fmaf(sP[jj], q_s[jj * QSTR + tid], acc);
      float cval = c_s[tid];
      __bf16* Gr = G + ((size_t)b * 256 + t) * 2560;
      Gr[tid]        = (__bf16)cval;
      Gr[512 + tid]  = (__bf16)acc;
      Gr[1024 + tid] = (__bf16)(cval * acc);
    }
    __syncthreads();
  }
}

// ---------------------------------------------------------------------------
// q2c tail
// ---------------------------------------------------------------------------
__global__ __launch_bounds__(256) void k_att_tail(
    const float* __restrict__ c, const float* __restrict__ smax_g,
    __bf16* __restrict__ G)
{
  __shared__ float w_s[256];
  __shared__ float red[8];
  const int b = blockIdx.x, tid = threadIdx.x;
  const int lane = tid & 63, wv = tid >> 6;
  float v = smax_g[b * 256 + tid];
  float m = v;
  #pragma unroll
  for (int off = 32; off; off >>= 1) m = fmaxf(m, __shfl_xor(m, off));
  if (lane == 0) red[wv] = m;
  __syncthreads();
  m = fmaxf(fmaxf(red[0], red[1]), fmaxf(red[2], red[3]));
  float e = __expf(v - m);
  float s = e;
  #pragma unroll
  for (int off = 32; off; off >>= 1) s += __shfl_xor(s, off);
  if (lane == 0) red[4 + wv] = s;
  __syncthreads();
  s = red[4] + red[5] + red[6] + red[7];
  w_s[tid] = e / s;
  __syncthreads();
  float q0 = 0.f, q1 = 0.f;
  for (int t = 0; t < 256; ++t) {
    const float* cr = c + ((size_t)b * 256 + t) * 512;
    q0 = fmaf(w_s[t], cr[tid], q0);
    q1 = fmaf(w_s[t], cr[tid + 256], q1);
  }
  for (int t = 0; t < 256; ++t) {
    const float* cr = c + ((size_t)b * 256 + t) * 512;
    __bf16* Gr = G + ((size_t)b * 256 + t) * 2560 + 1536;
    Gr[tid]       = (__bf16)(cr[tid] * q0);
    Gr[tid + 256] = (__bf16)(cr[tid + 256] * q1);
  }
}

// ---------------------------------------------------------------------------
// GEMM: C[M,1536] = A[M,K] @ Bw[1536,K]^T + bias, bf16 output.
// ---------------------------------------------------------------------------
__global__ __launch_bounds__(256) void gemm_bt(
    const __bf16* __restrict__ A, int lda,
    const __bf16* __restrict__ Bw, const float* __restrict__ bias,
    __bf16* __restrict__ C, int K)
{
  __shared__ __align__(16) __bf16 As[4096], Bs[4096];
  const int tid = threadIdx.x;
  const int lane = tid & 63, w = tid >> 6;
  const int l15 = lane & 15, lq = lane >> 4;
  const int wm = w >> 1, wn = w & 1;
  const size_t bm = (size_t)blockIdx.x * 128;
  const size_t bn = (size_t)blockIdx.y * 128;
  const int srow = tid >> 2, skg = tid & 3;
  const __bf16* Ag0 = A + (bm + srow) * lda + skg * 8;
  const __bf16* Ag1 = Ag0 + (size_t)64 * lda;
  const __bf16* Bg0 = Bw + (bn + srow) * (size_t)K + skg * 8;
  const __bf16* Bg1 = Bg0 + (size_t)64 * K;
  f32x4 acc[4][4] = {};
  const int nkt = K >> 5;
  for (int kt = 0; kt < nkt; ++kt) {
    const int ko = kt * 32;
    bf16x8 av0 = *(const bf16x8*)(Ag0 + ko);
    bf16x8 av1 = *(const bf16x8*)(Ag1 + ko);
    bf16x8 bv0 = *(const bf16x8*)(Bg0 + ko);
    bf16x8 bv1 = *(const bf16x8*)(Bg1 + ko);
    __syncthreads();
    *(bf16x8*)&As[(skg * 128 + srow) * 8] = av0;
    *(bf16x8*)&As[(skg * 128 + srow + 64) * 8] = av1;
    *(bf16x8*)&Bs[(skg * 128 + srow) * 8] = bv0;
    *(bf16x8*)&Bs[(skg * 128 + srow + 64) * 8] = bv1;
    __syncthreads();
    bf16x8 af[4], bfv[4];
    #pragma unroll
    for (int f = 0; f < 4; ++f) {
      af[f]  = *(const bf16x8*)&As[(lq * 128 + wm * 64 + f * 16 + l15) * 8];
      bfv[f] = *(const bf16x8*)&Bs[(lq * 128 + wn * 64 + f * 16 + l15) * 8];
    }
    #pragma unroll
    for (int fm = 0; fm < 4; ++fm)
      #pragma unroll
      for (int fn = 0; fn < 4; ++fn)
        acc[fm][fn] = __builtin_amdgcn_mfma_f32_16x16x32_bf16(af[fm], bfv[fn], acc[fm][fn], 0, 0, 0);
  }
  float bv[4];
  #pragma unroll
  for (int fn = 0; fn < 4; ++fn) bv[fn] = bias[bn + wn * 64 + fn * 16 + l15];
  #pragma unroll
  for (int fm = 0; fm < 4; ++fm)
    #pragma unroll
    for (int fn = 0; fn < 4; ++fn)
      #pragma unroll
      for (int r = 0; r < 4; ++r) {
        size_t row = bm + wm * 64 + fm * 16 + lq * 4 + r;
        size_t col = bn + wn * 64 + fn * 16 + l15;
        C[row * 1536 + col] = (__bf16)(acc[fm][fn][r] + bv[fn]);
      }
}

// ---------------------------------------------------------------------------
// GRU recurrence v5: 17/48 chunks LDS-cached (139KB), 31 streamed coalesced
// from L2; rcp-based gates (no precise-div sequences); coalesced ys epilogue
// (1 b128 LDS read + 1 dwordx4 store per thread) issued after the barrier.
// ---------------------------------------------------------------------------
#define GRU_WC 17
#define GRU_LDS_BYTES (GRU_WC * 8 * 1024 + 16896)
__global__ __launch_bounds__(512) void gru_rec(
    const __bf16* __restrict__ gi, const __bf16* __restrict__ wstream,
    const float* __restrict__ bhh, __bf16* __restrict__ ys, int ys_stride,
    float* __restrict__ out_final)
{
  constexpr int HSTR = 264;
  extern __shared__ __align__(16) char smem[];
  __bf16* wlds = (__bf16*)smem;                          // GRU_WC KB per wave
  __bf16* hl   = (__bf16*)(smem + GRU_WC * 8 * 1024);    // 2 * 16*HSTR bf16
  const int tid = threadIdx.x;
  const int w = tid >> 6, lane = tid & 63;
  const int l15 = lane & 15, lq = lane >> 4;
  const int dir = blockIdx.y;
  const int b0 = blockIdx.x * 16;

  for (int i = tid; i < 2 * 16 * HSTR; i += 512) hl[i] = (__bf16)0.0f;

  const __bf16* wbase = wstream + ((size_t)(dir * 8 + w)) * (48 * 64 * 8);
  // cache chunks 0..GRU_WC-1 (early ks-slices: first MFMAs run from LDS
  // while the 31 streamed chunks are still in flight)
  #pragma unroll
  for (int c0 = 0; c0 < GRU_WC; ++c0)
    *(bf16x8*)&wlds[((w * GRU_WC + c0) * 64 + lane) * 8] =
        *(const bf16x8*)(wbase + ((size_t)(c0 * 64 + lane)) * 8);

  float bhn0 = bhh[dir * 768 + w * 96 + l15 * 6 + 2];
  float bhn1 = bhh[dir * 768 + w * 96 + l15 * 6 + 5];

  const unsigned gofs = (unsigned)(b0 + lq * 4) * (256u * 1536u) + (unsigned)dir * 768u
                      + (unsigned)w * 96u + (unsigned)l15 * 6u;
  // coalesced ys epilogue mapping: thread -> (batch row, 8-elem d block)
  const int yrow = tid >> 5, yd0 = (tid & 31) * 8;

  float hprev[2][4] = {};
  int cur = 0;
  __syncthreads();

  for (int s = 0; s < 256; ++s) {
    const int t = dir ? (255 - s) : s;
    // gi prefetch: 3 dwords x 4 batches
    unsigned gw[4][3];
    const unsigned gbase = gofs + (unsigned)t * 1536u;
    #pragma unroll
    for (int r = 0; r < 4; ++r) {
      const unsigned* p = (const unsigned*)(gi + (gbase + (unsigned)r * (256u * 1536u)));
      gw[r][0] = p[0]; gw[r][1] = p[1]; gw[r][2] = p[2];
    }
    // gh = h @ Whh'^T; chunks c<GRU_WC from LDS, rest streamed from L2
    f32x4 acc[2][3] = {};
    const __bf16* hb_ = &hl[cur * (16 * HSTR) + l15 * HSTR + lq * 8];
    #pragma unroll
    for (int ks = 0; ks < 8; ++ks) {
      bf16x8 af = *(const bf16x8*)(hb_ + ks * 32);
      #pragma unroll
      for (int j = 0; j < 6; ++j) {
        const int c = ks * 6 + j;
        bf16x8 wv;
        if (c < GRU_WC) wv = *(const bf16x8*)&wlds[((w * GRU_WC + c) * 64 + lane) * 8];
        else            wv = *(const bf16x8*)(wbase + ((size_t)(c * 64 + lane)) * 8);
        acc[j / 3][j % 3] = __builtin_amdgcn_mfma_f32_16x16x32_bf16(af, wv, acc[j / 3][j % 3], 0, 0, 0);
      }
    }
    // gates + h update (rcp-based, no div sequences)
    #pragma unroll
    for (int dg = 0; dg < 2; ++dg)
      #pragma unroll
      for (int r = 0; r < 4; ++r) {
        float ir, iz, in_;
        if (dg == 0) { ir = bflo(gw[r][0]); iz = bfhi(gw[r][0]); in_ = bflo(gw[r][1]); }
        else         { ir = bfhi(gw[r][1]); iz = bflo(gw[r][2]); in_ = bfhi(gw[r][2]); }
        float bn_ = dg ? bhn1 : bhn0;
        float eR = __expf(-(ir + acc[dg][0][r]));
        float rg = rcp_(1.0f + eR);
        float eZ = __expf(-(iz + acc[dg][1][r]));
        float zg = rcp_(1.0f + eZ);
        float a  = in_ + rg * (acc[dg][2][r] + bn_);
        a = fminf(fmaxf(a, -15.0f), 15.0f);
        float eN = __expf(-2.0f * a);
        float ng = (1.0f - eN) * rcp_(1.0f + eN);
        float h = ng + zg * (hprev[dg][r] - ng);
        hprev[dg][r] = h;
        hl[(cur ^ 1) * (16 * HSTR) + (lq * 4 + r) * HSTR + w * 32 + dg * 16 + l15] = (__bf16)h;
      }
    // raw barrier: order LDS only; global/weight loads stay in flight
    asm volatile("s_waitcnt lgkmcnt(0)\n\ts_barrier" ::: "memory");
    // coalesced ys write from the just-published h buffer
    if (ys) {
      bf16x8 hv = *(const bf16x8*)&hl[(cur ^ 1) * (16 * HSTR) + yrow * HSTR + yd0];
      *(bf16x8*)(ys + ((size_t)(b0 + yrow) * 256 + t) * ys_stride + dir * 256 + yd0) = hv;
    }
    cur ^= 1;
  }
  if (!ys) {
    #pragma unroll
    for (int dg = 0; dg < 2; ++dg)
      #pragma unroll
      for (int r = 0; r < 4; ++r)
        out_final[(size_t)(b0 + lq * 4 + r) * 512 + (dir ? 0 : 256) + w * 32 + dg * 16 + l15]
            = hprev[dg][r];
  }
}

// ---------------------------------------------------------------------------
extern "C" void kernel_launch(void* const* d_in, const int* in_sizes, int n_in,
                              void* d_out, int out_size, void* d_ws, size_t ws_size,
                              hipStream_t stream) {
  (void)in_sizes; (void)n_in; (void)out_size; (void)ws_size;
  const float* c  = (const float*)d_in[0];
  const float* q  = (const float*)d_in[1];
  const float* Ws = (const float*)d_in[4];
  const float* w_ih[4] = { (const float*)d_in[5], (const float*)d_in[8],
                           (const float*)d_in[11], (const float*)d_in[14] };
  const float* w_hh[4] = { (const float*)d_in[6], (const float*)d_in[9],
                           (const float*)d_in[12], (const float*)d_in[15] };
  const float* b_l[4]  = { (const float*)d_in[7], (const float*)d_in[10],
                           (const float*)d_in[13], (const float*)d_in[16] };
  const int Kin[4] = {2048, 512, 2560, 512};

  static int lds_set = 0;
  if (!lds_set) {
    hipFuncSetAttribute((const void*)gru_rec,
                        hipFuncAttributeMaxDynamicSharedMemorySize, GRU_LDS_BYTES);
    lds_set = 1;
  }

  char* ws = (char*)d_ws;
  size_t off = 0;
  auto alloc = [&](size_t bytes) -> void* {
    void* p = ws + off; off += (bytes + 255) & ~(size_t)255; return p;
  };
  __bf16* Gbuf = (__bf16*)alloc((size_t)16384 * 2560 * 2);  // [G | M] bf16
  __bf16* gi   = (__bf16*)alloc((size_t)16384 * 1536 * 2);  // gate-packed bf16
  __bf16* m0   = (__bf16*)alloc((size_t)16384 * 512 * 2);
  __bf16* r0   = (__bf16*)alloc((size_t)16384 * 512 * 2);
  __bf16* wihp[4]; __bf16* wstr[4]; float* bihp[4]; float* bhhp[4];
  for (int l = 0; l < 4; ++l) {
    wihp[l] = (__bf16*)alloc((size_t)1536 * Kin[l] * 2);
    wstr[l] = (__bf16*)alloc((size_t)1536 * 256 * 2);   // fragment-major stream
    bihp[l] = (float*)alloc(1536 * 4);
    bhhp[l] = (float*)alloc(1536 * 4);
  }
  float* e_g  = (float*)alloc(4096 * 4);
  float* a_g  = (float*)alloc(16384 * 4);
  float* smax = (float*)alloc(16384 * 4);

  for (int l = 0; l < 4; ++l)
    prep_layer<<<1536, 256, 0, stream>>>(w_ih[l], w_hh[l], b_l[l], Kin[l],
                                         wihp[l], wstr[l], bihp[l], bhhp[l]);
  k_dots<<<5120, 256, 0, stream>>>(c, q, Ws, a_g, e_g);
  k_att_main<<<dim3(2, 64), 512, 0, stream>>>(c, q, Ws, a_g, e_g, smax, Gbuf);
  k_att_tail<<<64, 256, 0, stream>>>(c, smax, Gbuf);

  // layer mod0: G(2048) -> m0
  gemm_bt<<<dim3(128, 12), 256, 0, stream>>>(Gbuf, 2560, wihp[0], bihp[0], gi, 2048);
  gru_rec<<<dim3(4, 2), 512, GRU_LDS_BYTES, stream>>>(gi, wstr[0], bhhp[0], m0, 512, nullptr);
  // layer mod1: m0(512) -> M (into Gbuf cols 2048:2560)
  gemm_bt<<<dim3(128, 12), 256, 0, stream>>>(m0, 512, wihp[1], bihp[1], gi, 512);
  gru_rec<<<dim3(4, 2), 512, GRU_LDS_BYTES, stream>>>(gi, wstr[1], bhhp[1], Gbuf + 2048, 2560, nullptr);
  // layer rep0: [G|M](2560) -> r0
  gemm_bt<<<dim3(128, 12), 256, 0, stream>>>(Gbuf, 2560, wihp[2], bihp[2], gi, 2560);
  gru_rec<<<dim3(4, 2), 512, GRU_LDS_BYTES, stream>>>(gi, wstr[2], bhhp[2], r0, 512, nullptr);
  // layer rep1: r0(512) -> final h only
  gemm_bt<<<dim3(128, 12), 256, 0, stream>>>(r0, 512, wihp[3], bihp[3], gi, 512);
  gru_rec<<<dim3(4, 2), 512, GRU_LDS_BYTES, stream>>>(gi, wstr[3], bhhp[3], nullptr, 0, (float*)d_out);
}